// Round 12
// baseline (261.881 us; speedup 1.0000x reference)
//
#include <hip/hip_runtime.h>

typedef __attribute__((ext_vector_type(8))) short frag8;
typedef __attribute__((ext_vector_type(4))) float f32x4;
typedef __attribute__((ext_vector_type(8))) unsigned short us8;
typedef __attribute__((ext_vector_type(4))) unsigned short us4;
typedef __attribute__((ext_vector_type(2))) unsigned int u32x2;

#define MFMA(a,b,c) __builtin_amdgcn_mfma_f32_16x16x32_bf16((a),(b),(c),0,0,0)
#define LOG2E 1.44269504f

__device__ __forceinline__ unsigned short f2bf(float f){
  unsigned int u = __builtin_bit_cast(unsigned int, f);
  u += 0x7fffu + ((u >> 16) & 1u);
  return (unsigned short)(u >> 16);
}

__device__ __forceinline__ float bf2f(unsigned short h){
  unsigned int u = ((unsigned int)h) << 16;
  return __builtin_bit_cast(float, u);
}

__device__ __forceinline__ unsigned int cvt_pk_bf16(float a, float b){
  unsigned int r;
  asm volatile("v_cvt_pk_bf16_f32 %0, %1, %2" : "=v"(r) : "v"(a), "v"(b));
  return r;
}

// ---------------- workspace layout (bytes) ----------------
#define OFF_XT   ((size_t)0)            // [8][4096][256] bf16 = 16777216
#define OFF_KT   ((size_t)16777216)     // [8][4096][64]  bf16 = 4194304
#define OFF_VCT  ((size_t)20971520)     // [8][64][4096]  bf16 = 4194304
#define OFF_QT   ((size_t)25165824)     // [8][4096][64]  bf16 = 4194304
#define OFF_O1T  ((size_t)29360128)     // [8][4096][64]  bf16 = 4194304
#define OFF_ZT   ((size_t)33554432)     // [8][4096][256] bf16 = 16777216
                                        // attn O-partials [4][8][4096][64] bf16 alias (exact fit)
#define OFF_WQ7  ((size_t)50331648)     // [49][32][64]  bf16 = 200704
#define OFF_WQ11 ((size_t)50532352)     // [121][32][64] bf16 = 495616
#define OFF_WC1  ((size_t)51027968)     // [256][256] bf16 = 131072
#define OFF_WC2  ((size_t)51159040)     // [256][256] bf16 = 131072
#define OFF_BC1  ((size_t)51290112)     // [256] f32 = 1024
#define OFF_WKB  ((size_t)51291136)     // [64][64] bf16 = 8192
#define OFF_WVB  ((size_t)51299328)     // [64][64] bf16 = 8192  (ends 51307520)
#define OFF_ML2  OFF_WQ7                // split-2 ml [2][8][4096][2] f32 = 524288
#define OFF_ML4  ((size_t)51307520)     // split-4 ml [4][8][4096][2] f32 = 1048576
#define WS_NEED4 ((size_t)(OFF_ML4 + 1048576))   // 52356096

// ---------------- prep: weights ----------------
__global__ __launch_bounds__(256) void prep_weights_kernel(
    const float* __restrict__ wdw1, const float* __restrict__ wdw2,
    const float* __restrict__ wc1, const float* __restrict__ bng,
    const float* __restrict__ bnb, const float* __restrict__ bnm,
    const float* __restrict__ bnv, const float* __restrict__ wc2,
    const float* __restrict__ wk, const float* __restrict__ wv,
    unsigned short* __restrict__ wq7, unsigned short* __restrict__ wq11,
    unsigned short* __restrict__ wc1b, unsigned short* __restrict__ wc2b,
    float* __restrict__ bc1, unsigned short* __restrict__ wkb,
    unsigned short* __restrict__ wvb){
  int i = blockIdx.x*256 + threadIdx.x;
  if (i < 100352){
    int o = i >> 11, rem = i & 2047;
    int co = rem >> 6, ci = rem & 63;
    int kh = o / 7, kw = o % 7;
    wq7[i] = f2bf(wdw1[(co*64 + ci)*49 + kh*7 + kw]);
  } else if (i < 348160){
    int j = i - 100352;
    int o = j >> 11, rem = j & 2047;
    int co = rem >> 6, ci = rem & 63;
    int kh = o / 11, kw = o % 11;
    wq11[j] = f2bf(wdw2[(co*64 + ci)*121 + kh*11 + kw]);
  } else if (i < 413696){
    int j = i - 348160;
    int co = j >> 8;
    float a = bng[co] * rsqrtf(bnv[co] + 1e-5f);
    wc1b[j] = f2bf(wc1[j] * a);
    if ((j & 255) == 0) bc1[co] = bnb[co] - bnm[co]*a;
  } else if (i < 479232){
    int j = i - 413696;
    wc2b[j] = f2bf(wc2[j]);
  } else if (i < 483328){
    int j = i - 479232;
    wkb[j] = f2bf(wk[j]);
  } else if (i < 487424){
    int j = i - 483328;
    wvb[j] = f2bf(wv[j]);
  }
}

// ---------------- prep: transpose x (NCHW f32 -> [b][n][c] bf16) ----------------
__global__ __launch_bounds__(256) void prep_x_kernel(const float* __restrict__ x,
                                                     unsigned short* __restrict__ xt){
  int g = blockIdx.x*256 + threadIdx.x;
  int b = g >> 12, n = g & 4095;
  int c0base = blockIdx.y * 64;
  const float* xp = x + (((size_t)b*256) << 12) + n;
  unsigned short* op = xt + (size_t)g*256;
  for (int c0 = c0base; c0 < c0base + 64; c0 += 8){
    us8 v;
    #pragma unroll
    for (int j = 0; j < 8; ++j) v[j] = f2bf(xp[(size_t)(c0+j) << 12]);
    *reinterpret_cast<us8*>(op + c0) = v;
  }
}

// ---------------- k / v  (1x1 convs via MFMA) ----------------
__global__ __launch_bounds__(256) void kv_kernel(const unsigned short* __restrict__ xt,
    const unsigned short* __restrict__ wkb, const unsigned short* __restrict__ wvb,
    const float* __restrict__ bk, const float* __restrict__ bv,
    unsigned short* __restrict__ kt, unsigned short* __restrict__ vct){
  int gid = blockIdx.x;
  int part = gid >> 9, t = gid & 511;
  int b = t >> 6, tile = t & 63;
  int lane = threadIdx.x & 63, wid = threadIdx.x >> 6;
  int lo = lane & 15, hi = lane >> 4;
  int n0 = tile*64 + wid*16;
  size_t bb = (size_t)b << 12;
  f32x4 acc[4];
  #pragma unroll
  for (int f = 0; f < 4; ++f) acc[f] = (f32x4){0.f,0.f,0.f,0.f};
  frag8 x0 = *reinterpret_cast<const frag8*>(xt + (bb + n0 + lo)*256 + 8*hi);
  frag8 x1 = *reinterpret_cast<const frag8*>(xt + (bb + n0 + lo)*256 + 32 + 8*hi);
  if (part == 0){
    #pragma unroll
    for (int nf = 0; nf < 4; ++nf){
      frag8 w0 = *reinterpret_cast<const frag8*>(wkb + (nf*16 + lo)*64 + 8*hi);
      frag8 w1 = *reinterpret_cast<const frag8*>(wkb + (nf*16 + lo)*64 + 32 + 8*hi);
      acc[nf] = MFMA(x0, w0, acc[nf]);
      acc[nf] = MFMA(x1, w1, acc[nf]);
    }
    #pragma unroll
    for (int nf = 0; nf < 4; ++nf){
      int co = nf*16 + lo;
      float bias = bk[co];
      #pragma unroll
      for (int r = 0; r < 4; ++r)
        kt[(bb + n0 + hi*4 + r)*64 + co] = f2bf(acc[nf][r] + bias);
    }
  } else {
    #pragma unroll
    for (int mf = 0; mf < 4; ++mf){
      frag8 w0 = *reinterpret_cast<const frag8*>(wvb + (mf*16 + lo)*64 + 8*hi);
      frag8 w1 = *reinterpret_cast<const frag8*>(wvb + (mf*16 + lo)*64 + 32 + 8*hi);
      acc[mf] = MFMA(w0, x0, acc[mf]);
      acc[mf] = MFMA(w1, x1, acc[mf]);
    }
    #pragma unroll
    for (int mf = 0; mf < 4; ++mf){
      #pragma unroll
      for (int r = 0; r < 4; ++r){
        int c = mf*16 + hi*4 + r;
        vct[(((size_t)b*64 + c) << 12) + n0 + lo] = f2bf(acc[mf][r] + bv[c]);
      }
    }
  }
}

// ---------------- Q convs (7x7 / 11x11), h-pair weight-stationary implicit GEMM --------
// Epilogue scales Q by log2(e) so attention can use exp2 (saves a mul per exp).
template<int KS>
__global__ __launch_bounds__(256) void conv_q_kernel(const unsigned short* __restrict__ xt,
    const unsigned short* __restrict__ wq, const float* __restrict__ bias,
    unsigned short* __restrict__ qt){
  constexpr int P = KS/2;
  constexpr int NR = (KS+1)/2;
  __shared__ unsigned short xs[NR*64*64];
  __shared__ float outst[2][64][33];
  int h0 = blockIdx.x*2, b = blockIdx.y;
  int tid = threadIdx.x, lane = tid & 63, wid = tid >> 6;
  int lo = lane & 15, hi = lane >> 4;
  int cofrag = wid & 1, hsel = wid >> 1;
  int h = h0 + hsel;
  f32x4 acc[4];
  #pragma unroll
  for (int nf = 0; nf < 4; ++nf) acc[nf] = (f32x4){0.f,0.f,0.f,0.f};
  const size_t xbase = ((size_t)b << 12) * 256;
  #pragma unroll
  for (int pass = 0; pass < 2; ++pass){
    const int srcBase = h0 - P + pass*NR;
    if (pass) __syncthreads();
    for (int idx = tid; idx < NR*512; idx += 256){
      int rl = idx >> 9, w = (idx >> 3) & 63, ch = idx & 7;
      int sr = srcBase + rl;
      us8 v = {0,0,0,0,0,0,0,0};
      if (sr >= 0 && sr < 64)
        v = *reinterpret_cast<const us8*>(xt + xbase + (size_t)(sr*64 + w)*256 + ch*8);
      int byte = (rl*64 + w)*128 + ((ch*16) ^ ((w & 7) << 4));
      *reinterpret_cast<us8*>((char*)xs + byte) = v;
    }
    __syncthreads();
    for (int rl = 0; rl < NR; ++rl){
      int dh = srcBase + rl - h + P;
      if (dh < 0 || dh >= KS) continue;
      frag8 wf[KS][2];
      int off0 = dh*KS;
      #pragma unroll
      for (int dw = 0; dw < KS; ++dw){
        #pragma unroll
        for (int ks = 0; ks < 2; ++ks)
          wf[dw][ks] = *reinterpret_cast<const frag8*>(
              wq + (size_t)(off0+dw)*2048 + (cofrag*16 + lo)*64 + ks*32 + 8*hi);
      }
      #pragma unroll
      for (int dw = 0; dw < KS; ++dw){
        #pragma unroll
        for (int nf = 0; nf < 4; ++nf){
          int w_out = nf*16 + lo;
          int wp = w_out + dw - P;
          frag8 bx0 = {0,0,0,0,0,0,0,0}, bx1 = {0,0,0,0,0,0,0,0};
          if (wp >= 0 && wp < 64){
            int rowb = (rl*64 + wp)*128;
            int sw = (wp & 7) << 4;
            bx0 = *reinterpret_cast<const frag8*>((char*)xs + rowb + ((hi*16) ^ sw));
            bx1 = *reinterpret_cast<const frag8*>((char*)xs + rowb + ((64 + hi*16) ^ sw));
          }
          acc[nf] = MFMA(wf[dw][0], bx0, acc[nf]);
          acc[nf] = MFMA(wf[dw][1], bx1, acc[nf]);
        }
      }
    }
  }
  #pragma unroll
  for (int nf = 0; nf < 4; ++nf){
    int w = nf*16 + lo;
    #pragma unroll
    for (int r = 0; r < 4; ++r)
      outst[hsel][w][cofrag*16 + hi*4 + r] = acc[nf][r];
  }
  __syncthreads();
  {
    int hs = tid >> 7, rem = tid & 127;
    int w = rem >> 1, c16 = (rem & 1)*16;
    int cobase = (KS == 7) ? 0 : 32;
    size_t qrow = (((size_t)b << 12) + (h0 + hs)*64 + w)*64;
    #pragma unroll
    for (int g = 0; g < 2; ++g){
      int c8 = c16 + g*8;
      us8 v;
      #pragma unroll
      for (int j = 0; j < 8; ++j)
        v[j] = f2bf((outst[hs][w][c8 + j] + bias[c8 + j]) * LOG2E);
      *reinterpret_cast<us8*>(qt + qrow + cobase + c8) = v;
    }
  }
}

// ---------------- flash attention: swapped QK^T, V direct from L2, exp2 softmax -------
// K double-buffered in LDS (shared by 4 waves); V B-frags loaded per-lane b128 straight
// from vct (L2/L3-resident, issued at tile-top so QK+softmax hides the latency).
// Q pre-scaled by log2e -> P = 2^(S'-m'); m' stored scaled, merge uses exp2.
template<int NSPLIT>
__global__ __launch_bounds__(256, 2) void attn_kernel(const unsigned short* __restrict__ qt,
    const unsigned short* __restrict__ kt, const unsigned short* __restrict__ vct,
    unsigned short* __restrict__ opart, float* __restrict__ mlpart){
  constexpr int TILES = 64 / NSPLIT;
  __shared__ unsigned short kls[2][64*64];
  __shared__ unsigned short pls[4][32*64];
  int b = blockIdx.y, half = blockIdx.z;
  int tid = threadIdx.x, lane = tid & 63, wid = tid >> 6;
  int lo = lane & 15, hi = lane >> 4;
  int q0 = blockIdx.x*128 + wid*32;
  const size_t bb = (size_t)b << 12;
  const int mtbase = half * TILES;
  const int sm = tid >> 3, sch = tid & 7;
  const int dstA = sm*128 + ((sch*16) ^ ((sm & 7) << 4));
  const int dstB = dstA + 32*128;
  char* pbase = (char*)pls[wid];
  const unsigned short* vb = vct + (((size_t)b*64) << 12);
  frag8 aq[2][2];
  #pragma unroll
  for (int mf = 0; mf < 2; ++mf)
    #pragma unroll
    for (int ks = 0; ks < 2; ++ks)
      aq[mf][ks] = *reinterpret_cast<const frag8*>(
          qt + (bb + q0 + mf*16 + lo)*64 + ks*32 + 8*hi);
  f32x4 o[2][4];
  #pragma unroll
  for (int mf = 0; mf < 2; ++mf)
    #pragma unroll
    for (int f = 0; f < 4; ++f) o[mf][f] = (f32x4){0.f,0.f,0.f,0.f};
  float mr[2]  = {-1e30f, -1e30f};
  float lr[2]  = {0.f, 0.f};
  float mrT[2][4];
  #pragma unroll
  for (int mf = 0; mf < 2; ++mf)
    #pragma unroll
    for (int r = 0; r < 4; ++r) mrT[mf][r] = -1e30f;
  us8 kr0, kr1;
  {
    int mt = mtbase;
    kr0 = *reinterpret_cast<const us8*>(kt + (bb + mt*64 + sm)*64 + sch*8);
    kr1 = *reinterpret_cast<const us8*>(kt + (bb + mt*64 + sm + 32)*64 + sch*8);
    *reinterpret_cast<us8*>((char*)kls[0] + dstA) = kr0;
    *reinterpret_cast<us8*>((char*)kls[0] + dstB) = kr1;
  }
  __syncthreads();
  int cur = 0;
  for (int t = 0; t < TILES; ++t){
    int mt = mtbase + t;
    // V fragments for this tile: per-lane b128 from global (L2-resident), issued early
    frag8 bvr[2][4];
    #pragma unroll
    for (int ks = 0; ks < 2; ++ks)
      #pragma unroll
      for (int cf = 0; cf < 4; ++cf)
        bvr[ks][cf] = *reinterpret_cast<const frag8*>(
            vb + (((size_t)(cf*16 + lo)) << 12) + mt*64 + ks*32 + hi*8);
    // K prefetch for next tile
    if (t < TILES-1){
      int mtn = mt + 1;
      kr0 = *reinterpret_cast<const us8*>(kt + (bb + mtn*64 + sm)*64 + sch*8);
      kr1 = *reinterpret_cast<const us8*>(kt + (bb + mtn*64 + sm + 32)*64 + sch*8);
    }
    // QK^T swapped: S^T[m][q] = K · Q   (S already scaled by log2e via Q)
    f32x4 s[2][4];
    #pragma unroll
    for (int mf = 0; mf < 2; ++mf)
      #pragma unroll
      for (int f = 0; f < 4; ++f) s[mf][f] = (f32x4){0.f,0.f,0.f,0.f};
    #pragma unroll
    for (int nf = 0; nf < 4; ++nf){
      int m = nf*16 + lo;
      int sw = (m & 7) << 4;
      frag8 b0 = *reinterpret_cast<const frag8*>((char*)kls[cur] + m*128 + ((hi*16) ^ sw));
      frag8 b1 = *reinterpret_cast<const frag8*>((char*)kls[cur] + m*128 + ((64 + hi*16) ^ sw));
      s[0][nf] = MFMA(b0, aq[0][0], s[0][nf]);
      s[0][nf] = MFMA(b1, aq[0][1], s[0][nf]);
      s[1][nf] = MFMA(b0, aq[1][0], s[1][nf]);
      s[1][nf] = MFMA(b1, aq[1][1], s[1][nf]);
    }
    // defer-max on per-lane partials (scaled domain: THR = 8*log2e)
    float pm[2];
    #pragma unroll
    for (int mf = 0; mf < 2; ++mf){
      float a0 = fmaxf(fmaxf(s[mf][0][0], s[mf][0][1]), fmaxf(s[mf][0][2], s[mf][0][3]));
      float a1 = fmaxf(fmaxf(s[mf][1][0], s[mf][1][1]), fmaxf(s[mf][1][2], s[mf][1][3]));
      float a2 = fmaxf(fmaxf(s[mf][2][0], s[mf][2][1]), fmaxf(s[mf][2][2], s[mf][2][3]));
      float a3 = fmaxf(fmaxf(s[mf][3][0], s[mf][3][1]), fmaxf(s[mf][3][2], s[mf][3][3]));
      pm[mf] = fmaxf(fmaxf(a0, a1), fmaxf(a2, a3));
    }
    float growth = fmaxf(pm[0] - mr[0], pm[1] - mr[1]);
    if (!__all(growth <= 11.5416f)){
      float rmax[2] = {pm[0], pm[1]};
      #pragma unroll
      for (int mf = 0; mf < 2; ++mf){
        rmax[mf] = fmaxf(rmax[mf], __shfl_xor(rmax[mf], 16));
        rmax[mf] = fmaxf(rmax[mf], __shfl_xor(rmax[mf], 32));
        float mn = fmaxf(mr[mf], rmax[mf]);
        lr[mf] *= exp2f(mr[mf] - mn);
        mr[mf] = mn;
      }
      #pragma unroll
      for (int mf = 0; mf < 2; ++mf)
        #pragma unroll
        for (int r = 0; r < 4; ++r){
          float mnT = __shfl(mr[mf], hi*4 + r);
          float scT = exp2f(mrT[mf][r] - mnT);
          mrT[mf][r] = mnT;
          #pragma unroll
          for (int cf = 0; cf < 4; ++cf) o[mf][cf][r] *= scT;
        }
    }
    // P = 2^(S'-m'); per-lane l partial; packed b64 P-writes
    #pragma unroll
    for (int mf = 0; mf < 2; ++mf){
      float acc = 0.f;
      #pragma unroll
      for (int nf = 0; nf < 4; ++nf){
        #pragma unroll
        for (int r = 0; r < 4; ++r){
          s[mf][nf][r] = exp2f(s[mf][nf][r] - mr[mf]);
          acc += s[mf][nf][r];
        }
        u32x2 w;
        w[0] = cvt_pk_bf16(s[mf][nf][0], s[mf][nf][1]);
        w[1] = cvt_pk_bf16(s[mf][nf][2], s[mf][nf][3]);
        *reinterpret_cast<u32x2*>(pbase + (mf*16 + lo)*128 +
            ((nf*32 + hi*8) ^ ((lo & 7) << 4))) = w;
      }
      lr[mf] += acc;
    }
    // PV: A = P (swizzled b128 rows from LDS), B = V frags already in registers
    #pragma unroll
    for (int ks = 0; ks < 2; ++ks){
      frag8 ap0 = *reinterpret_cast<const frag8*>(
          pbase + lo*128 + ((ks*64 + hi*16) ^ ((lo & 7) << 4)));
      frag8 ap1 = *reinterpret_cast<const frag8*>(
          pbase + (16 + lo)*128 + ((ks*64 + hi*16) ^ ((lo & 7) << 4)));
      #pragma unroll
      for (int cf = 0; cf < 4; ++cf){
        o[0][cf] = MFMA(ap0, bvr[ks][cf], o[0][cf]);
        o[1][cf] = MFMA(ap1, bvr[ks][cf], o[1][cf]);
      }
    }
    if (t < TILES-1){
      *reinterpret_cast<us8*>((char*)kls[cur^1] + dstA) = kr0;
      *reinterpret_cast<us8*>((char*)kls[cur^1] + dstB) = kr1;
    }
    __syncthreads();
    cur ^= 1;
  }
  #pragma unroll
  for (int mf = 0; mf < 2; ++mf){
    lr[mf] += __shfl_xor(lr[mf], 16);
    lr[mf] += __shfl_xor(lr[mf], 32);
  }
  size_t pb = ((size_t)(half*8 + b) << 12);
  #pragma unroll
  for (int mf = 0; mf < 2; ++mf){
    #pragma unroll
    for (int cf = 0; cf < 4; ++cf)
      #pragma unroll
      for (int r = 0; r < 4; ++r)
        opart[(pb + q0 + mf*16 + hi*4 + r)*64 + cf*16 + lo] = f2bf(o[mf][cf][r]);
    if (hi == 0){
      size_t idx = pb + q0 + mf*16 + lo;
      mlpart[idx*2]     = mr[mf];
      mlpart[idx*2 + 1] = lr[mf];
    }
  }
}

// ---------------- merge of the KV splits (bf16 partials, exp2 domain) ----------------
template<int NSPLIT>
__global__ __launch_bounds__(256) void merge_kernel(const unsigned short* __restrict__ opart,
    const float* __restrict__ mlpart, unsigned short* __restrict__ o1t){
  int g = blockIdx.x*256 + threadIdx.x;
  int c4 = g & 15, q = (g >> 4) & 4095, b = g >> 16;
  size_t idx[NSPLIT];
  float m[NSPLIT], l[NSPLIT];
  float M = -1e30f;
  #pragma unroll
  for (int p = 0; p < NSPLIT; ++p){
    idx[p] = ((size_t)(p*8 + b) << 12) + q;
    m[p] = mlpart[idx[p]*2];
    l[p] = mlpart[idx[p]*2 + 1];
    M = fmaxf(M, m[p]);
  }
  float denom = 0.f, w[NSPLIT];
  #pragma unroll
  for (int p = 0; p < NSPLIT; ++p){
    w[p] = exp2f(m[p] - M);
    denom += w[p] * l[p];
  }
  float inv = 1.0f / denom;
  f32x4 acc = (f32x4){0.f,0.f,0.f,0.f};
  #pragma unroll
  for (int p = 0; p < NSPLIT; ++p){
    us4 a = *reinterpret_cast<const us4*>(opart + idx[p]*64 + c4*4);
    float wp = w[p] * inv;
    #pragma unroll
    for (int j = 0; j < 4; ++j) acc[j] += wp * bf2f(a[j]);
  }
  unsigned short outv[4];
  #pragma unroll
  for (int j = 0; j < 4; ++j) outv[j] = f2bf(acc[j]);
  *reinterpret_cast<ulonglong1*>(o1t + (((size_t)b << 12) + q)*64 + c4*4) =
      *reinterpret_cast<ulonglong1*>(outv);
}

// ---------------- c1 (concat + 1x1 conv + BN + SiLU) ----------------
__global__ __launch_bounds__(256) void c1_kernel(const unsigned short* __restrict__ o1t,
    const unsigned short* __restrict__ xt, const unsigned short* __restrict__ wc1b,
    const float* __restrict__ bc1, unsigned short* __restrict__ zt){
  int b = blockIdx.y;
  int q0 = blockIdx.x*64 + (threadIdx.x >> 6)*16;
  int lane = threadIdx.x & 63, lo = lane & 15, hi = lane >> 4;
  size_t bb = (size_t)b << 12;
  f32x4 acc[16];
  #pragma unroll
  for (int nf = 0; nf < 16; ++nf) acc[nf] = (f32x4){0.f,0.f,0.f,0.f};
  #pragma unroll
  for (int ks = 0; ks < 8; ++ks){
    int ci0 = ks*32 + 8*hi;
    frag8 a;
    if (ks < 2) a = *reinterpret_cast<const frag8*>(o1t + (bb + q0 + lo)*64 + ci0);
    else        a = *reinterpret_cast<const frag8*>(xt  + (bb + q0 + lo)*256 + ci0);
    #pragma unroll
    for (int nf = 0; nf < 16; ++nf){
      frag8 w = *reinterpret_cast<const frag8*>(wc1b + (nf*16 + lo)*256 + ci0);
      acc[nf] = MFMA(a, w, acc[nf]);
    }
  }
  #pragma unroll
  for (int nf = 0; nf < 16; ++nf){
    int co = nf*16 + lo;
    float bias = bc1[co];
    #pragma unroll
    for (int r = 0; r < 4; ++r){
      float y = acc[nf][r] + bias;
      y = y / (1.0f + __expf(-y));
      zt[(bb + q0 + hi*4 + r)*256 + co] = f2bf(y);
    }
  }
}

// ---------------- c2 (1x1 conv, weight-stationary, fp32 NCHW out) ----------------
__global__ __launch_bounds__(256) void c2_kernel(const unsigned short* __restrict__ zt,
    const unsigned short* __restrict__ wc2b, const float* __restrict__ bc2,
    float* __restrict__ out){
  int b = blockIdx.y;
  int q0 = blockIdx.x*128 + (threadIdx.x >> 6)*32;
  int lane = threadIdx.x & 63, lo = lane & 15, hi = lane >> 4;
  size_t bb = (size_t)b << 12;
  f32x4 acc[16][2];
  #pragma unroll
  for (int mf = 0; mf < 16; ++mf){
    acc[mf][0] = (f32x4){0.f,0.f,0.f,0.f};
    acc[mf][1] = (f32x4){0.f,0.f,0.f,0.f};
  }
  #pragma unroll
  for (int ks = 0; ks < 8; ++ks){
    int ci0 = ks*32 + 8*hi;
    frag8 bz0 = *reinterpret_cast<const frag8*>(zt + (bb + q0 + lo)*256 + ci0);
    frag8 bz1 = *reinterpret_cast<const frag8*>(zt + (bb + q0 + 16 + lo)*256 + ci0);
    #pragma unroll
    for (int mf = 0; mf < 16; ++mf){
      frag8 aw = *reinterpret_cast<const frag8*>(wc2b + (mf*16 + lo)*256 + ci0);
      acc[mf][0] = MFMA(aw, bz0, acc[mf][0]);
      acc[mf][1] = MFMA(aw, bz1, acc[mf][1]);
    }
  }
  #pragma unroll
  for (int mf = 0; mf < 16; ++mf){
    #pragma unroll
    for (int r = 0; r < 4; ++r){
      int co = mf*16 + hi*4 + r;
      float bias = bc2[co];
      float* op = out + (((size_t)b*256 + co) << 12) + q0 + lo;
      op[0]  = acc[mf][0][r] + bias;
      op[16] = acc[mf][1][r] + bias;
    }
  }
}

// ---------------- launch ----------------
extern "C" void kernel_launch(void* const* d_in, const int* in_sizes, int n_in,
                              void* d_out, int out_size, void* d_ws, size_t ws_size,
                              hipStream_t stream){
  const float* x    = (const float*)d_in[0];
  const float* wdw1 = (const float*)d_in[1];
  const float* bdw1 = (const float*)d_in[2];
  const float* wdw2 = (const float*)d_in[3];
  const float* bdw2 = (const float*)d_in[4];
  const float* wk   = (const float*)d_in[5];
  const float* bk   = (const float*)d_in[6];
  const float* wv   = (const float*)d_in[7];
  const float* bv   = (const float*)d_in[8];
  const float* wc1  = (const float*)d_in[9];
  const float* bng  = (const float*)d_in[10];
  const float* bnb  = (const float*)d_in[11];
  const float* bnm  = (const float*)d_in[12];
  const float* bnv  = (const float*)d_in[13];
  const float* wc2  = (const float*)d_in[14];
  const float* bc2  = (const float*)d_in[15];
  char* ws = (char*)d_ws;
  unsigned short* xt   = (unsigned short*)(ws + OFF_XT);
  unsigned short* ktp  = (unsigned short*)(ws + OFF_KT);
  unsigned short* vct  = (unsigned short*)(ws + OFF_VCT);
  unsigned short* qtp  = (unsigned short*)(ws + OFF_QT);
  unsigned short* o1t  = (unsigned short*)(ws + OFF_O1T);
  unsigned short* zt   = (unsigned short*)(ws + OFF_ZT);
  unsigned short* wq7  = (unsigned short*)(ws + OFF_WQ7);
  unsigned short* wq11 = (unsigned short*)(ws + OFF_WQ11);
  unsigned short* wc1b = (unsigned short*)(ws + OFF_WC1);
  unsigned short* wc2b = (unsigned short*)(ws + OFF_WC2);
  float*          bc1  = (float*)(ws + OFF_BC1);
  unsigned short* wkb  = (unsigned short*)(ws + OFF_WKB);
  unsigned short* wvb  = (unsigned short*)(ws + OFF_WVB);
  unsigned short* opart = (unsigned short*)(ws + OFF_ZT);  // bf16 partials alias zt
  const bool big = (ws_size >= WS_NEED4);
  float*          mlp   = (float*)(ws + (big ? OFF_ML4 : OFF_ML2));

  prep_weights_kernel<<<1904, 256, 0, stream>>>(wdw1, wdw2, wc1, bng, bnb, bnm, bnv,
                                                wc2, wk, wv, wq7, wq11, wc1b, wc2b,
                                                bc1, wkb, wvb);
  prep_x_kernel<<<dim3(128, 4), 256, 0, stream>>>(x, xt);
  kv_kernel<<<1024, 256, 0, stream>>>(xt, wkb, wvb, bk, bv, ktp, vct);
  conv_q_kernel<7><<<dim3(32, 8), 256, 0, stream>>>(xt, wq7, bdw1, qtp);
  conv_q_kernel<11><<<dim3(32, 8), 256, 0, stream>>>(xt, wq11, bdw2, qtp);
  if (big){
    attn_kernel<4><<<dim3(32, 8, 4), 256, 0, stream>>>(qtp, ktp, vct, opart, mlp);
    merge_kernel<4><<<2048, 256, 0, stream>>>(opart, mlp, o1t);
  } else {
    attn_kernel<2><<<dim3(32, 8, 2), 256, 0, stream>>>(qtp, ktp, vct, opart, mlp);
    merge_kernel<2><<<2048, 256, 0, stream>>>(opart, mlp, o1t);
  }
  c1_kernel<<<dim3(64, 8), 256, 0, stream>>>(o1t, xt, wc1b, bc1, zt);
  c2_kernel<<<dim3(32, 8), 256, 0, stream>>>(zt, wc2b, bc2, (float*)d_out);
}

// Round 13
// 246.756 us; speedup vs baseline: 1.0613x; 1.0613x over previous
//
#include <hip/hip_runtime.h>

typedef __attribute__((ext_vector_type(8))) short frag8;
typedef __attribute__((ext_vector_type(4))) float f32x4;
typedef __attribute__((ext_vector_type(8))) unsigned short us8;
typedef __attribute__((ext_vector_type(4))) unsigned short us4;
typedef __attribute__((ext_vector_type(2))) unsigned int u32x2;

#define MFMA(a,b,c) __builtin_amdgcn_mfma_f32_16x16x32_bf16((a),(b),(c),0,0,0)
#define LOG2E 1.44269504f

__device__ __forceinline__ unsigned short f2bf(float f){
  unsigned int u = __builtin_bit_cast(unsigned int, f);
  u += 0x7fffu + ((u >> 16) & 1u);
  return (unsigned short)(u >> 16);
}

__device__ __forceinline__ float bf2f(unsigned short h){
  unsigned int u = ((unsigned int)h) << 16;
  return __builtin_bit_cast(float, u);
}

__device__ __forceinline__ unsigned int cvt_pk_bf16(float a, float b){
  unsigned int r;
  asm volatile("v_cvt_pk_bf16_f32 %0, %1, %2" : "=v"(r) : "v"(a), "v"(b));
  return r;
}

// ---------------- workspace layout (bytes) ----------------
#define OFF_XT   ((size_t)0)            // [8][4096][256] bf16 = 16777216
#define OFF_KT   ((size_t)16777216)     // [8][4096][64]  bf16 = 4194304
#define OFF_VCT  ((size_t)20971520)     // [8][64][4096]  bf16 = 4194304
#define OFF_QT   ((size_t)25165824)     // [8][4096][64]  bf16 = 4194304
#define OFF_O1T  ((size_t)29360128)     // [8][4096][64]  bf16 = 4194304
#define OFF_ZT   ((size_t)33554432)     // [8][4096][256] bf16 = 16777216
                                        // attn O-partials [4][8][4096][64] bf16 alias (exact fit)
#define OFF_WQ7  ((size_t)50331648)     // [49][32][64]  bf16 = 200704
#define OFF_WQ11 ((size_t)50532352)     // [121][32][64] bf16 = 495616
#define OFF_WC1  ((size_t)51027968)     // [256][256] bf16 = 131072
#define OFF_WC2  ((size_t)51159040)     // [256][256] bf16 = 131072
#define OFF_BC1  ((size_t)51290112)     // [256] f32 = 1024
#define OFF_WKB  ((size_t)51291136)     // [64][64] bf16 = 8192
#define OFF_WVB  ((size_t)51299328)     // [64][64] bf16 = 8192  (ends 51307520)
#define OFF_ML2  OFF_WQ7                // split-2 ml [2][8][4096][2] f32 = 524288
#define OFF_ML4  ((size_t)51307520)     // split-4 ml [4][8][4096][2] f32 = 1048576
#define WS_NEED4 ((size_t)(OFF_ML4 + 1048576))   // 52356096

// ---------------- prep: weights ----------------
__global__ __launch_bounds__(256) void prep_weights_kernel(
    const float* __restrict__ wdw1, const float* __restrict__ wdw2,
    const float* __restrict__ wc1, const float* __restrict__ bng,
    const float* __restrict__ bnb, const float* __restrict__ bnm,
    const float* __restrict__ bnv, const float* __restrict__ wc2,
    const float* __restrict__ wk, const float* __restrict__ wv,
    unsigned short* __restrict__ wq7, unsigned short* __restrict__ wq11,
    unsigned short* __restrict__ wc1b, unsigned short* __restrict__ wc2b,
    float* __restrict__ bc1, unsigned short* __restrict__ wkb,
    unsigned short* __restrict__ wvb){
  int i = blockIdx.x*256 + threadIdx.x;
  if (i < 100352){
    int o = i >> 11, rem = i & 2047;
    int co = rem >> 6, ci = rem & 63;
    int kh = o / 7, kw = o % 7;
    wq7[i] = f2bf(wdw1[(co*64 + ci)*49 + kh*7 + kw]);
  } else if (i < 348160){
    int j = i - 100352;
    int o = j >> 11, rem = j & 2047;
    int co = rem >> 6, ci = rem & 63;
    int kh = o / 11, kw = o % 11;
    wq11[j] = f2bf(wdw2[(co*64 + ci)*121 + kh*11 + kw]);
  } else if (i < 413696){
    int j = i - 348160;
    int co = j >> 8;
    float a = bng[co] * rsqrtf(bnv[co] + 1e-5f);
    wc1b[j] = f2bf(wc1[j] * a);
    if ((j & 255) == 0) bc1[co] = bnb[co] - bnm[co]*a;
  } else if (i < 479232){
    int j = i - 413696;
    wc2b[j] = f2bf(wc2[j]);
  } else if (i < 483328){
    int j = i - 479232;
    wkb[j] = f2bf(wk[j]);
  } else if (i < 487424){
    int j = i - 483328;
    wvb[j] = f2bf(wv[j]);
  }
}

// ---------------- prep: transpose x (NCHW f32 -> [b][n][c] bf16) ----------------
__global__ __launch_bounds__(256) void prep_x_kernel(const float* __restrict__ x,
                                                     unsigned short* __restrict__ xt){
  int g = blockIdx.x*256 + threadIdx.x;
  int b = g >> 12, n = g & 4095;
  int c0base = blockIdx.y * 64;
  const float* xp = x + (((size_t)b*256) << 12) + n;
  unsigned short* op = xt + (size_t)g*256;
  for (int c0 = c0base; c0 < c0base + 64; c0 += 8){
    us8 v;
    #pragma unroll
    for (int j = 0; j < 8; ++j) v[j] = f2bf(xp[(size_t)(c0+j) << 12]);
    *reinterpret_cast<us8*>(op + c0) = v;
  }
}

// ---------------- k / v  (1x1 convs via MFMA) ----------------
__global__ __launch_bounds__(256) void kv_kernel(const unsigned short* __restrict__ xt,
    const unsigned short* __restrict__ wkb, const unsigned short* __restrict__ wvb,
    const float* __restrict__ bk, const float* __restrict__ bv,
    unsigned short* __restrict__ kt, unsigned short* __restrict__ vct){
  int gid = blockIdx.x;
  int part = gid >> 9, t = gid & 511;
  int b = t >> 6, tile = t & 63;
  int lane = threadIdx.x & 63, wid = threadIdx.x >> 6;
  int lo = lane & 15, hi = lane >> 4;
  int n0 = tile*64 + wid*16;
  size_t bb = (size_t)b << 12;
  f32x4 acc[4];
  #pragma unroll
  for (int f = 0; f < 4; ++f) acc[f] = (f32x4){0.f,0.f,0.f,0.f};
  frag8 x0 = *reinterpret_cast<const frag8*>(xt + (bb + n0 + lo)*256 + 8*hi);
  frag8 x1 = *reinterpret_cast<const frag8*>(xt + (bb + n0 + lo)*256 + 32 + 8*hi);
  if (part == 0){
    #pragma unroll
    for (int nf = 0; nf < 4; ++nf){
      frag8 w0 = *reinterpret_cast<const frag8*>(wkb + (nf*16 + lo)*64 + 8*hi);
      frag8 w1 = *reinterpret_cast<const frag8*>(wkb + (nf*16 + lo)*64 + 32 + 8*hi);
      acc[nf] = MFMA(x0, w0, acc[nf]);
      acc[nf] = MFMA(x1, w1, acc[nf]);
    }
    #pragma unroll
    for (int nf = 0; nf < 4; ++nf){
      int co = nf*16 + lo;
      float bias = bk[co];
      #pragma unroll
      for (int r = 0; r < 4; ++r)
        kt[(bb + n0 + hi*4 + r)*64 + co] = f2bf(acc[nf][r] + bias);
    }
  } else {
    #pragma unroll
    for (int mf = 0; mf < 4; ++mf){
      frag8 w0 = *reinterpret_cast<const frag8*>(wvb + (mf*16 + lo)*64 + 8*hi);
      frag8 w1 = *reinterpret_cast<const frag8*>(wvb + (mf*16 + lo)*64 + 32 + 8*hi);
      acc[mf] = MFMA(w0, x0, acc[mf]);
      acc[mf] = MFMA(w1, x1, acc[mf]);
    }
    #pragma unroll
    for (int mf = 0; mf < 4; ++mf){
      #pragma unroll
      for (int r = 0; r < 4; ++r){
        int c = mf*16 + hi*4 + r;
        vct[(((size_t)b*64 + c) << 12) + n0 + lo] = f2bf(acc[mf][r] + bv[c]);
      }
    }
  }
}

// ---------------- Q convs (7x7 / 11x11), h-pair weight-stationary implicit GEMM --------
// Epilogue scales Q by log2(e) so attention can use exp2 (saves a mul per exp).
template<int KS>
__global__ __launch_bounds__(256) void conv_q_kernel(const unsigned short* __restrict__ xt,
    const unsigned short* __restrict__ wq, const float* __restrict__ bias,
    unsigned short* __restrict__ qt){
  constexpr int P = KS/2;
  constexpr int NR = (KS+1)/2;
  __shared__ unsigned short xs[NR*64*64];
  __shared__ float outst[2][64][33];
  int h0 = blockIdx.x*2, b = blockIdx.y;
  int tid = threadIdx.x, lane = tid & 63, wid = tid >> 6;
  int lo = lane & 15, hi = lane >> 4;
  int cofrag = wid & 1, hsel = wid >> 1;
  int h = h0 + hsel;
  f32x4 acc[4];
  #pragma unroll
  for (int nf = 0; nf < 4; ++nf) acc[nf] = (f32x4){0.f,0.f,0.f,0.f};
  const size_t xbase = ((size_t)b << 12) * 256;
  #pragma unroll
  for (int pass = 0; pass < 2; ++pass){
    const int srcBase = h0 - P + pass*NR;
    if (pass) __syncthreads();
    for (int idx = tid; idx < NR*512; idx += 256){
      int rl = idx >> 9, w = (idx >> 3) & 63, ch = idx & 7;
      int sr = srcBase + rl;
      us8 v = {0,0,0,0,0,0,0,0};
      if (sr >= 0 && sr < 64)
        v = *reinterpret_cast<const us8*>(xt + xbase + (size_t)(sr*64 + w)*256 + ch*8);
      int byte = (rl*64 + w)*128 + ((ch*16) ^ ((w & 7) << 4));
      *reinterpret_cast<us8*>((char*)xs + byte) = v;
    }
    __syncthreads();
    for (int rl = 0; rl < NR; ++rl){
      int dh = srcBase + rl - h + P;
      if (dh < 0 || dh >= KS) continue;
      frag8 wf[KS][2];
      int off0 = dh*KS;
      #pragma unroll
      for (int dw = 0; dw < KS; ++dw){
        #pragma unroll
        for (int ks = 0; ks < 2; ++ks)
          wf[dw][ks] = *reinterpret_cast<const frag8*>(
              wq + (size_t)(off0+dw)*2048 + (cofrag*16 + lo)*64 + ks*32 + 8*hi);
      }
      #pragma unroll
      for (int dw = 0; dw < KS; ++dw){
        #pragma unroll
        for (int nf = 0; nf < 4; ++nf){
          int w_out = nf*16 + lo;
          int wp = w_out + dw - P;
          frag8 bx0 = {0,0,0,0,0,0,0,0}, bx1 = {0,0,0,0,0,0,0,0};
          if (wp >= 0 && wp < 64){
            int rowb = (rl*64 + wp)*128;
            int sw = (wp & 7) << 4;
            bx0 = *reinterpret_cast<const frag8*>((char*)xs + rowb + ((hi*16) ^ sw));
            bx1 = *reinterpret_cast<const frag8*>((char*)xs + rowb + ((64 + hi*16) ^ sw));
          }
          acc[nf] = MFMA(wf[dw][0], bx0, acc[nf]);
          acc[nf] = MFMA(wf[dw][1], bx1, acc[nf]);
        }
      }
    }
  }
  #pragma unroll
  for (int nf = 0; nf < 4; ++nf){
    int w = nf*16 + lo;
    #pragma unroll
    for (int r = 0; r < 4; ++r)
      outst[hsel][w][cofrag*16 + hi*4 + r] = acc[nf][r];
  }
  __syncthreads();
  {
    int hs = tid >> 7, rem = tid & 127;
    int w = rem >> 1, c16 = (rem & 1)*16;
    int cobase = (KS == 7) ? 0 : 32;
    size_t qrow = (((size_t)b << 12) + (h0 + hs)*64 + w)*64;
    #pragma unroll
    for (int g = 0; g < 2; ++g){
      int c8 = c16 + g*8;
      us8 v;
      #pragma unroll
      for (int j = 0; j < 8; ++j)
        v[j] = f2bf((outst[hs][w][c8 + j] + bias[c8 + j]) * LOG2E);
      *reinterpret_cast<us8*>(qt + qrow + cobase + c8) = v;
    }
  }
}

// ---------------- flash attention: R10 structure + exp2 softmax ----------------
// K,V double-buffered in LDS with reg prefetch; swapped QK^T; swizzled P round-trip.
// Q pre-scaled by log2e -> P = 2^(S'-m'); m' stored scaled, merge uses exp2.
template<int NSPLIT>
__global__ __launch_bounds__(256, 2) void attn_kernel(const unsigned short* __restrict__ qt,
    const unsigned short* __restrict__ kt, const unsigned short* __restrict__ vct,
    unsigned short* __restrict__ opart, float* __restrict__ mlpart){
  constexpr int TILES = 64 / NSPLIT;
  __shared__ unsigned short kls[2][64*64];
  __shared__ unsigned short vls[2][64*64];
  __shared__ unsigned short pls[4][32*64];
  int b = blockIdx.y, half = blockIdx.z;
  int tid = threadIdx.x, lane = tid & 63, wid = tid >> 6;
  int lo = lane & 15, hi = lane >> 4;
  int q0 = blockIdx.x*128 + wid*32;
  const size_t bb = (size_t)b << 12;
  const int mtbase = half * TILES;
  const int sm = tid >> 3, sch = tid & 7;
  const int dstA = sm*128 + ((sch*16) ^ ((sm & 7) << 4));
  const int dstB = dstA + 32*128;
  char* pbase = (char*)pls[wid];
  frag8 aq[2][2];
  #pragma unroll
  for (int mf = 0; mf < 2; ++mf)
    #pragma unroll
    for (int ks = 0; ks < 2; ++ks)
      aq[mf][ks] = *reinterpret_cast<const frag8*>(
          qt + (bb + q0 + mf*16 + lo)*64 + ks*32 + 8*hi);
  f32x4 o[2][4];
  #pragma unroll
  for (int mf = 0; mf < 2; ++mf)
    #pragma unroll
    for (int f = 0; f < 4; ++f) o[mf][f] = (f32x4){0.f,0.f,0.f,0.f};
  float mr[2]  = {-1e30f, -1e30f};
  float lr[2]  = {0.f, 0.f};
  float mrT[2][4];
  #pragma unroll
  for (int mf = 0; mf < 2; ++mf)
    #pragma unroll
    for (int r = 0; r < 4; ++r) mrT[mf][r] = -1e30f;
  us8 kr0, kr1, vr0, vr1;
  {
    int mt = mtbase;
    kr0 = *reinterpret_cast<const us8*>(kt + (bb + mt*64 + sm)*64 + sch*8);
    kr1 = *reinterpret_cast<const us8*>(kt + (bb + mt*64 + sm + 32)*64 + sch*8);
    vr0 = *reinterpret_cast<const us8*>(vct + (((size_t)b*64 + sm) << 12) + mt*64 + sch*8);
    vr1 = *reinterpret_cast<const us8*>(vct + (((size_t)b*64 + sm + 32) << 12) + mt*64 + sch*8);
    *reinterpret_cast<us8*>((char*)kls[0] + dstA) = kr0;
    *reinterpret_cast<us8*>((char*)kls[0] + dstB) = kr1;
    *reinterpret_cast<us8*>((char*)vls[0] + dstA) = vr0;
    *reinterpret_cast<us8*>((char*)vls[0] + dstB) = vr1;
  }
  __syncthreads();
  int cur = 0;
  for (int t = 0; t < TILES; ++t){
    if (t < TILES-1){
      int mt = mtbase + t + 1;
      kr0 = *reinterpret_cast<const us8*>(kt + (bb + mt*64 + sm)*64 + sch*8);
      kr1 = *reinterpret_cast<const us8*>(kt + (bb + mt*64 + sm + 32)*64 + sch*8);
      vr0 = *reinterpret_cast<const us8*>(vct + (((size_t)b*64 + sm) << 12) + mt*64 + sch*8);
      vr1 = *reinterpret_cast<const us8*>(vct + (((size_t)b*64 + sm + 32) << 12) + mt*64 + sch*8);
    }
    // QK^T swapped: S^T[m][q] = K · Q   (S already scaled by log2e via Q)
    f32x4 s[2][4];
    #pragma unroll
    for (int mf = 0; mf < 2; ++mf)
      #pragma unroll
      for (int f = 0; f < 4; ++f) s[mf][f] = (f32x4){0.f,0.f,0.f,0.f};
    #pragma unroll
    for (int nf = 0; nf < 4; ++nf){
      int m = nf*16 + lo;
      int sw = (m & 7) << 4;
      frag8 b0 = *reinterpret_cast<const frag8*>((char*)kls[cur] + m*128 + ((hi*16) ^ sw));
      frag8 b1 = *reinterpret_cast<const frag8*>((char*)kls[cur] + m*128 + ((64 + hi*16) ^ sw));
      s[0][nf] = MFMA(b0, aq[0][0], s[0][nf]);
      s[0][nf] = MFMA(b1, aq[0][1], s[0][nf]);
      s[1][nf] = MFMA(b0, aq[1][0], s[1][nf]);
      s[1][nf] = MFMA(b1, aq[1][1], s[1][nf]);
    }
    // defer-max on per-lane partials (scaled domain: THR = 8*log2e)
    float pm[2];
    #pragma unroll
    for (int mf = 0; mf < 2; ++mf){
      float a0 = fmaxf(fmaxf(s[mf][0][0], s[mf][0][1]), fmaxf(s[mf][0][2], s[mf][0][3]));
      float a1 = fmaxf(fmaxf(s[mf][1][0], s[mf][1][1]), fmaxf(s[mf][1][2], s[mf][1][3]));
      float a2 = fmaxf(fmaxf(s[mf][2][0], s[mf][2][1]), fmaxf(s[mf][2][2], s[mf][2][3]));
      float a3 = fmaxf(fmaxf(s[mf][3][0], s[mf][3][1]), fmaxf(s[mf][3][2], s[mf][3][3]));
      pm[mf] = fmaxf(fmaxf(a0, a1), fmaxf(a2, a3));
    }
    float growth = fmaxf(pm[0] - mr[0], pm[1] - mr[1]);
    if (!__all(growth <= 11.5416f)){
      float rmax[2] = {pm[0], pm[1]};
      #pragma unroll
      for (int mf = 0; mf < 2; ++mf){
        rmax[mf] = fmaxf(rmax[mf], __shfl_xor(rmax[mf], 16));
        rmax[mf] = fmaxf(rmax[mf], __shfl_xor(rmax[mf], 32));
        float mn = fmaxf(mr[mf], rmax[mf]);
        lr[mf] *= exp2f(mr[mf] - mn);
        mr[mf] = mn;
      }
      #pragma unroll
      for (int mf = 0; mf < 2; ++mf)
        #pragma unroll
        for (int r = 0; r < 4; ++r){
          float mnT = __shfl(mr[mf], hi*4 + r);
          float scT = exp2f(mrT[mf][r] - mnT);
          mrT[mf][r] = mnT;
          #pragma unroll
          for (int cf = 0; cf < 4; ++cf) o[mf][cf][r] *= scT;
        }
    }
    // P = 2^(S'-m'); per-lane l partial; packed b64 P-writes
    #pragma unroll
    for (int mf = 0; mf < 2; ++mf){
      float acc = 0.f;
      #pragma unroll
      for (int nf = 0; nf < 4; ++nf){
        #pragma unroll
        for (int r = 0; r < 4; ++r){
          s[mf][nf][r] = exp2f(s[mf][nf][r] - mr[mf]);
          acc += s[mf][nf][r];
        }
        u32x2 w;
        w[0] = cvt_pk_bf16(s[mf][nf][0], s[mf][nf][1]);
        w[1] = cvt_pk_bf16(s[mf][nf][2], s[mf][nf][3]);
        *reinterpret_cast<u32x2*>(pbase + (mf*16 + lo)*128 +
            ((nf*32 + hi*8) ^ ((lo & 7) << 4))) = w;
      }
      lr[mf] += acc;
    }
    // PV: A = P (swizzled b128 rows), B = V frags from LDS
    #pragma unroll
    for (int ks = 0; ks < 2; ++ks){
      frag8 ap0 = *reinterpret_cast<const frag8*>(
          pbase + lo*128 + ((ks*64 + hi*16) ^ ((lo & 7) << 4)));
      frag8 ap1 = *reinterpret_cast<const frag8*>(
          pbase + (16 + lo)*128 + ((ks*64 + hi*16) ^ ((lo & 7) << 4)));
      #pragma unroll
      for (int cf = 0; cf < 4; ++cf){
        int c = cf*16 + lo;
        frag8 bv = *reinterpret_cast<const frag8*>(
            (char*)vls[cur] + c*128 + ((ks*64 + hi*16) ^ ((c & 7) << 4)));
        o[0][cf] = MFMA(ap0, bv, o[0][cf]);
        o[1][cf] = MFMA(ap1, bv, o[1][cf]);
      }
    }
    if (t < TILES-1){
      *reinterpret_cast<us8*>((char*)kls[cur^1] + dstA) = kr0;
      *reinterpret_cast<us8*>((char*)kls[cur^1] + dstB) = kr1;
      *reinterpret_cast<us8*>((char*)vls[cur^1] + dstA) = vr0;
      *reinterpret_cast<us8*>((char*)vls[cur^1] + dstB) = vr1;
    }
    __syncthreads();
    cur ^= 1;
  }
  #pragma unroll
  for (int mf = 0; mf < 2; ++mf){
    lr[mf] += __shfl_xor(lr[mf], 16);
    lr[mf] += __shfl_xor(lr[mf], 32);
  }
  size_t pb = ((size_t)(half*8 + b) << 12);
  #pragma unroll
  for (int mf = 0; mf < 2; ++mf){
    #pragma unroll
    for (int cf = 0; cf < 4; ++cf)
      #pragma unroll
      for (int r = 0; r < 4; ++r)
        opart[(pb + q0 + mf*16 + hi*4 + r)*64 + cf*16 + lo] = f2bf(o[mf][cf][r]);
    if (hi == 0){
      size_t idx = pb + q0 + mf*16 + lo;
      mlpart[idx*2]     = mr[mf];
      mlpart[idx*2 + 1] = lr[mf];
    }
  }
}

// ---------------- merge of the KV splits (bf16 partials, exp2 domain) ----------------
template<int NSPLIT>
__global__ __launch_bounds__(256) void merge_kernel(const unsigned short* __restrict__ opart,
    const float* __restrict__ mlpart, unsigned short* __restrict__ o1t){
  int g = blockIdx.x*256 + threadIdx.x;
  int c4 = g & 15, q = (g >> 4) & 4095, b = g >> 16;
  size_t idx[NSPLIT];
  float m[NSPLIT], l[NSPLIT];
  float M = -1e30f;
  #pragma unroll
  for (int p = 0; p < NSPLIT; ++p){
    idx[p] = ((size_t)(p*8 + b) << 12) + q;
    m[p] = mlpart[idx[p]*2];
    l[p] = mlpart[idx[p]*2 + 1];
    M = fmaxf(M, m[p]);
  }
  float denom = 0.f, w[NSPLIT];
  #pragma unroll
  for (int p = 0; p < NSPLIT; ++p){
    w[p] = exp2f(m[p] - M);
    denom += w[p] * l[p];
  }
  float inv = 1.0f / denom;
  f32x4 acc = (f32x4){0.f,0.f,0.f,0.f};
  #pragma unroll
  for (int p = 0; p < NSPLIT; ++p){
    us4 a = *reinterpret_cast<const us4*>(opart + idx[p]*64 + c4*4);
    float wp = w[p] * inv;
    #pragma unroll
    for (int j = 0; j < 4; ++j) acc[j] += wp * bf2f(a[j]);
  }
  unsigned short outv[4];
  #pragma unroll
  for (int j = 0; j < 4; ++j) outv[j] = f2bf(acc[j]);
  *reinterpret_cast<ulonglong1*>(o1t + (((size_t)b << 12) + q)*64 + c4*4) =
      *reinterpret_cast<ulonglong1*>(outv);
}

// ---------------- c1 (concat + 1x1 conv + BN + SiLU) ----------------
__global__ __launch_bounds__(256) void c1_kernel(const unsigned short* __restrict__ o1t,
    const unsigned short* __restrict__ xt, const unsigned short* __restrict__ wc1b,
    const float* __restrict__ bc1, unsigned short* __restrict__ zt){
  int b = blockIdx.y;
  int q0 = blockIdx.x*64 + (threadIdx.x >> 6)*16;
  int lane = threadIdx.x & 63, lo = lane & 15, hi = lane >> 4;
  size_t bb = (size_t)b << 12;
  f32x4 acc[16];
  #pragma unroll
  for (int nf = 0; nf < 16; ++nf) acc[nf] = (f32x4){0.f,0.f,0.f,0.f};
  #pragma unroll
  for (int ks = 0; ks < 8; ++ks){
    int ci0 = ks*32 + 8*hi;
    frag8 a;
    if (ks < 2) a = *reinterpret_cast<const frag8*>(o1t + (bb + q0 + lo)*64 + ci0);
    else        a = *reinterpret_cast<const frag8*>(xt  + (bb + q0 + lo)*256 + ci0);
    #pragma unroll
    for (int nf = 0; nf < 16; ++nf){
      frag8 w = *reinterpret_cast<const frag8*>(wc1b + (nf*16 + lo)*256 + ci0);
      acc[nf] = MFMA(a, w, acc[nf]);
    }
  }
  #pragma unroll
  for (int nf = 0; nf < 16; ++nf){
    int co = nf*16 + lo;
    float bias = bc1[co];
    #pragma unroll
    for (int r = 0; r < 4; ++r){
      float y = acc[nf][r] + bias;
      y = y / (1.0f + __expf(-y));
      zt[(bb + q0 + hi*4 + r)*256 + co] = f2bf(y);
    }
  }
}

// ---------------- c2 (1x1 conv, weight-stationary, fp32 NCHW out) ----------------
__global__ __launch_bounds__(256) void c2_kernel(const unsigned short* __restrict__ zt,
    const unsigned short* __restrict__ wc2b, const float* __restrict__ bc2,
    float* __restrict__ out){
  int b = blockIdx.y;
  int q0 = blockIdx.x*128 + (threadIdx.x >> 6)*32;
  int lane = threadIdx.x & 63, lo = lane & 15, hi = lane >> 4;
  size_t bb = (size_t)b << 12;
  f32x4 acc[16][2];
  #pragma unroll
  for (int mf = 0; mf < 16; ++mf){
    acc[mf][0] = (f32x4){0.f,0.f,0.f,0.f};
    acc[mf][1] = (f32x4){0.f,0.f,0.f,0.f};
  }
  #pragma unroll
  for (int ks = 0; ks < 8; ++ks){
    int ci0 = ks*32 + 8*hi;
    frag8 bz0 = *reinterpret_cast<const frag8*>(zt + (bb + q0 + lo)*256 + ci0);
    frag8 bz1 = *reinterpret_cast<const frag8*>(zt + (bb + q0 + 16 + lo)*256 + ci0);
    #pragma unroll
    for (int mf = 0; mf < 16; ++mf){
      frag8 aw = *reinterpret_cast<const frag8*>(wc2b + (mf*16 + lo)*256 + ci0);
      acc[mf][0] = MFMA(aw, bz0, acc[mf][0]);
      acc[mf][1] = MFMA(aw, bz1, acc[mf][1]);
    }
  }
  #pragma unroll
  for (int mf = 0; mf < 16; ++mf){
    #pragma unroll
    for (int r = 0; r < 4; ++r){
      int co = mf*16 + hi*4 + r;
      float bias = bc2[co];
      float* op = out + (((size_t)b*256 + co) << 12) + q0 + lo;
      op[0]  = acc[mf][0][r] + bias;
      op[16] = acc[mf][1][r] + bias;
    }
  }
}

// ---------------- launch ----------------
extern "C" void kernel_launch(void* const* d_in, const int* in_sizes, int n_in,
                              void* d_out, int out_size, void* d_ws, size_t ws_size,
                              hipStream_t stream){
  const float* x    = (const float*)d_in[0];
  const float* wdw1 = (const float*)d_in[1];
  const float* bdw1 = (const float*)d_in[2];
  const float* wdw2 = (const float*)d_in[3];
  const float* bdw2 = (const float*)d_in[4];
  const float* wk   = (const float*)d_in[5];
  const float* bk   = (const float*)d_in[6];
  const float* wv   = (const float*)d_in[7];
  const float* bv   = (const float*)d_in[8];
  const float* wc1  = (const float*)d_in[9];
  const float* bng  = (const float*)d_in[10];
  const float* bnb  = (const float*)d_in[11];
  const float* bnm  = (const float*)d_in[12];
  const float* bnv  = (const float*)d_in[13];
  const float* wc2  = (const float*)d_in[14];
  const float* bc2  = (const float*)d_in[15];
  char* ws = (char*)d_ws;
  unsigned short* xt   = (unsigned short*)(ws + OFF_XT);
  unsigned short* ktp  = (unsigned short*)(ws + OFF_KT);
  unsigned short* vct  = (unsigned short*)(ws + OFF_VCT);
  unsigned short* qtp  = (unsigned short*)(ws + OFF_QT);
  unsigned short* o1t  = (unsigned short*)(ws + OFF_O1T);
  unsigned short* zt   = (unsigned short*)(ws + OFF_ZT);
  unsigned short* wq7  = (unsigned short*)(ws + OFF_WQ7);
  unsigned short* wq11 = (unsigned short*)(ws + OFF_WQ11);
  unsigned short* wc1b = (unsigned short*)(ws + OFF_WC1);
  unsigned short* wc2b = (unsigned short*)(ws + OFF_WC2);
  float*          bc1  = (float*)(ws + OFF_BC1);
  unsigned short* wkb  = (unsigned short*)(ws + OFF_WKB);
  unsigned short* wvb  = (unsigned short*)(ws + OFF_WVB);
  unsigned short* opart = (unsigned short*)(ws + OFF_ZT);  // bf16 partials alias zt
  const bool big = (ws_size >= WS_NEED4);
  float*          mlp   = (float*)(ws + (big ? OFF_ML4 : OFF_ML2));

  prep_weights_kernel<<<1904, 256, 0, stream>>>(wdw1, wdw2, wc1, bng, bnb, bnm, bnv,
                                                wc2, wk, wv, wq7, wq11, wc1b, wc2b,
                                                bc1, wkb, wvb);
  prep_x_kernel<<<dim3(128, 4), 256, 0, stream>>>(x, xt);
  kv_kernel<<<1024, 256, 0, stream>>>(xt, wkb, wvb, bk, bv, ktp, vct);
  conv_q_kernel<7><<<dim3(32, 8), 256, 0, stream>>>(xt, wq7, bdw1, qtp);
  conv_q_kernel<11><<<dim3(32, 8), 256, 0, stream>>>(xt, wq11, bdw2, qtp);
  if (big){
    attn_kernel<4><<<dim3(32, 8, 4), 256, 0, stream>>>(qtp, ktp, vct, opart, mlp);
    merge_kernel<4><<<2048, 256, 0, stream>>>(opart, mlp, o1t);
  } else {
    attn_kernel<2><<<dim3(32, 8, 2), 256, 0, stream>>>(qtp, ktp, vct, opart, mlp);
    merge_kernel<2><<<2048, 256, 0, stream>>>(opart, mlp, o1t);
  }
  c1_kernel<<<dim3(64, 8), 256, 0, stream>>>(o1t, xt, wc1b, bc1, zt);
  c2_kernel<<<dim3(32, 8), 256, 0, stream>>>(zt, wc2b, bc2, (float*)d_out);
}

// Round 14
// 230.486 us; speedup vs baseline: 1.1362x; 1.0706x over previous
//
#include <hip/hip_runtime.h>

typedef __attribute__((ext_vector_type(8))) short frag8;
typedef __attribute__((ext_vector_type(4))) float f32x4;
typedef __attribute__((ext_vector_type(8))) unsigned short us8;
typedef __attribute__((ext_vector_type(4))) unsigned short us4;
typedef __attribute__((ext_vector_type(2))) unsigned int u32x2;

#define MFMA(a,b,c) __builtin_amdgcn_mfma_f32_16x16x32_bf16((a),(b),(c),0,0,0)
#define LOG2E 1.44269504f
#define EXP2(x) __builtin_amdgcn_exp2f(x)   // bare v_exp_f32 (computes 2^x)

__device__ __forceinline__ unsigned short f2bf(float f){
  unsigned int u = __builtin_bit_cast(unsigned int, f);
  u += 0x7fffu + ((u >> 16) & 1u);
  return (unsigned short)(u >> 16);
}

__device__ __forceinline__ float bf2f(unsigned short h){
  unsigned int u = ((unsigned int)h) << 16;
  return __builtin_bit_cast(float, u);
}

__device__ __forceinline__ unsigned int cvt_pk_bf16(float a, float b){
  unsigned int r;
  asm volatile("v_cvt_pk_bf16_f32 %0, %1, %2" : "=v"(r) : "v"(a), "v"(b));
  return r;
}

// ---------------- workspace layout (bytes) ----------------
#define OFF_XT   ((size_t)0)            // [8][4096][256] bf16 = 16777216
#define OFF_KT   ((size_t)16777216)     // [8][4096][64]  bf16 = 4194304
#define OFF_VCT  ((size_t)20971520)     // [8][64][4096]  bf16 = 4194304
#define OFF_QT   ((size_t)25165824)     // [8][4096][64]  bf16 = 4194304
#define OFF_O1T  ((size_t)29360128)     // [8][4096][64]  bf16 = 4194304
#define OFF_ZT   ((size_t)33554432)     // [8][4096][256] bf16 = 16777216
                                        // attn O-partials [4][8][4096][64] bf16 alias (exact fit)
#define OFF_WQ7  ((size_t)50331648)     // [49][32][64]  bf16 = 200704
#define OFF_WQ11 ((size_t)50532352)     // [121][32][64] bf16 = 495616
#define OFF_WC1  ((size_t)51027968)     // [256][256] bf16 = 131072
#define OFF_WC2  ((size_t)51159040)     // [256][256] bf16 = 131072
#define OFF_BC1  ((size_t)51290112)     // [256] f32 = 1024
#define OFF_WKB  ((size_t)51291136)     // [64][64] bf16 = 8192
#define OFF_WVB  ((size_t)51299328)     // [64][64] bf16 = 8192  (ends 51307520)
#define OFF_ML2  OFF_WQ7                // split-2 ml [2][8][4096][2] f32 = 524288
#define OFF_ML4  ((size_t)51307520)     // split-4 ml [4][8][4096][2] f32 = 1048576
#define WS_NEED4 ((size_t)(OFF_ML4 + 1048576))   // 52356096

// ---------------- prep: weights ----------------
__global__ __launch_bounds__(256) void prep_weights_kernel(
    const float* __restrict__ wdw1, const float* __restrict__ wdw2,
    const float* __restrict__ wc1, const float* __restrict__ bng,
    const float* __restrict__ bnb, const float* __restrict__ bnm,
    const float* __restrict__ bnv, const float* __restrict__ wc2,
    const float* __restrict__ wk, const float* __restrict__ wv,
    unsigned short* __restrict__ wq7, unsigned short* __restrict__ wq11,
    unsigned short* __restrict__ wc1b, unsigned short* __restrict__ wc2b,
    float* __restrict__ bc1, unsigned short* __restrict__ wkb,
    unsigned short* __restrict__ wvb){
  int i = blockIdx.x*256 + threadIdx.x;
  if (i < 100352){
    int o = i >> 11, rem = i & 2047;
    int co = rem >> 6, ci = rem & 63;
    int kh = o / 7, kw = o % 7;
    wq7[i] = f2bf(wdw1[(co*64 + ci)*49 + kh*7 + kw]);
  } else if (i < 348160){
    int j = i - 100352;
    int o = j >> 11, rem = j & 2047;
    int co = rem >> 6, ci = rem & 63;
    int kh = o / 11, kw = o % 11;
    wq11[j] = f2bf(wdw2[(co*64 + ci)*121 + kh*11 + kw]);
  } else if (i < 413696){
    int j = i - 348160;
    int co = j >> 8;
    float a = bng[co] * rsqrtf(bnv[co] + 1e-5f);
    wc1b[j] = f2bf(wc1[j] * a);
    if ((j & 255) == 0) bc1[co] = bnb[co] - bnm[co]*a;
  } else if (i < 479232){
    int j = i - 413696;
    wc2b[j] = f2bf(wc2[j]);
  } else if (i < 483328){
    int j = i - 479232;
    wkb[j] = f2bf(wk[j]);
  } else if (i < 487424){
    int j = i - 483328;
    wvb[j] = f2bf(wv[j]);
  }
}

// ---------------- prep: transpose x (NCHW f32 -> [b][n][c] bf16) ----------------
__global__ __launch_bounds__(256) void prep_x_kernel(const float* __restrict__ x,
                                                     unsigned short* __restrict__ xt){
  int g = blockIdx.x*256 + threadIdx.x;
  int b = g >> 12, n = g & 4095;
  int c0base = blockIdx.y * 64;
  const float* xp = x + (((size_t)b*256) << 12) + n;
  unsigned short* op = xt + (size_t)g*256;
  for (int c0 = c0base; c0 < c0base + 64; c0 += 8){
    us8 v;
    #pragma unroll
    for (int j = 0; j < 8; ++j) v[j] = f2bf(xp[(size_t)(c0+j) << 12]);
    *reinterpret_cast<us8*>(op + c0) = v;
  }
}

// ---------------- k / v  (1x1 convs via MFMA) ----------------
__global__ __launch_bounds__(256) void kv_kernel(const unsigned short* __restrict__ xt,
    const unsigned short* __restrict__ wkb, const unsigned short* __restrict__ wvb,
    const float* __restrict__ bk, const float* __restrict__ bv,
    unsigned short* __restrict__ kt, unsigned short* __restrict__ vct){
  int gid = blockIdx.x;
  int part = gid >> 9, t = gid & 511;
  int b = t >> 6, tile = t & 63;
  int lane = threadIdx.x & 63, wid = threadIdx.x >> 6;
  int lo = lane & 15, hi = lane >> 4;
  int n0 = tile*64 + wid*16;
  size_t bb = (size_t)b << 12;
  f32x4 acc[4];
  #pragma unroll
  for (int f = 0; f < 4; ++f) acc[f] = (f32x4){0.f,0.f,0.f,0.f};
  frag8 x0 = *reinterpret_cast<const frag8*>(xt + (bb + n0 + lo)*256 + 8*hi);
  frag8 x1 = *reinterpret_cast<const frag8*>(xt + (bb + n0 + lo)*256 + 32 + 8*hi);
  if (part == 0){
    #pragma unroll
    for (int nf = 0; nf < 4; ++nf){
      frag8 w0 = *reinterpret_cast<const frag8*>(wkb + (nf*16 + lo)*64 + 8*hi);
      frag8 w1 = *reinterpret_cast<const frag8*>(wkb + (nf*16 + lo)*64 + 32 + 8*hi);
      acc[nf] = MFMA(x0, w0, acc[nf]);
      acc[nf] = MFMA(x1, w1, acc[nf]);
    }
    #pragma unroll
    for (int nf = 0; nf < 4; ++nf){
      int co = nf*16 + lo;
      float bias = bk[co];
      #pragma unroll
      for (int r = 0; r < 4; ++r)
        kt[(bb + n0 + hi*4 + r)*64 + co] = f2bf(acc[nf][r] + bias);
    }
  } else {
    #pragma unroll
    for (int mf = 0; mf < 4; ++mf){
      frag8 w0 = *reinterpret_cast<const frag8*>(wvb + (mf*16 + lo)*64 + 8*hi);
      frag8 w1 = *reinterpret_cast<const frag8*>(wvb + (mf*16 + lo)*64 + 32 + 8*hi);
      acc[mf] = MFMA(w0, x0, acc[mf]);
      acc[mf] = MFMA(w1, x1, acc[mf]);
    }
    #pragma unroll
    for (int mf = 0; mf < 4; ++mf){
      #pragma unroll
      for (int r = 0; r < 4; ++r){
        int c = mf*16 + hi*4 + r;
        vct[(((size_t)b*64 + c) << 12) + n0 + lo] = f2bf(acc[mf][r] + bv[c]);
      }
    }
  }
}

// ---------------- Q convs (7x7 / 11x11), h-pair weight-stationary implicit GEMM --------
// Epilogue scales Q by log2(e) so attention can use the bare v_exp_f32 (2^x).
template<int KS>
__global__ __launch_bounds__(256) void conv_q_kernel(const unsigned short* __restrict__ xt,
    const unsigned short* __restrict__ wq, const float* __restrict__ bias,
    unsigned short* __restrict__ qt){
  constexpr int P = KS/2;
  constexpr int NR = (KS+1)/2;
  __shared__ unsigned short xs[NR*64*64];
  __shared__ float outst[2][64][33];
  int h0 = blockIdx.x*2, b = blockIdx.y;
  int tid = threadIdx.x, lane = tid & 63, wid = tid >> 6;
  int lo = lane & 15, hi = lane >> 4;
  int cofrag = wid & 1, hsel = wid >> 1;
  int h = h0 + hsel;
  f32x4 acc[4];
  #pragma unroll
  for (int nf = 0; nf < 4; ++nf) acc[nf] = (f32x4){0.f,0.f,0.f,0.f};
  const size_t xbase = ((size_t)b << 12) * 256;
  #pragma unroll
  for (int pass = 0; pass < 2; ++pass){
    const int srcBase = h0 - P + pass*NR;
    if (pass) __syncthreads();
    for (int idx = tid; idx < NR*512; idx += 256){
      int rl = idx >> 9, w = (idx >> 3) & 63, ch = idx & 7;
      int sr = srcBase + rl;
      us8 v = {0,0,0,0,0,0,0,0};
      if (sr >= 0 && sr < 64)
        v = *reinterpret_cast<const us8*>(xt + xbase + (size_t)(sr*64 + w)*256 + ch*8);
      int byte = (rl*64 + w)*128 + ((ch*16) ^ ((w & 7) << 4));
      *reinterpret_cast<us8*>((char*)xs + byte) = v;
    }
    __syncthreads();
    for (int rl = 0; rl < NR; ++rl){
      int dh = srcBase + rl - h + P;
      if (dh < 0 || dh >= KS) continue;
      frag8 wf[KS][2];
      int off0 = dh*KS;
      #pragma unroll
      for (int dw = 0; dw < KS; ++dw){
        #pragma unroll
        for (int ks = 0; ks < 2; ++ks)
          wf[dw][ks] = *reinterpret_cast<const frag8*>(
              wq + (size_t)(off0+dw)*2048 + (cofrag*16 + lo)*64 + ks*32 + 8*hi);
      }
      #pragma unroll
      for (int dw = 0; dw < KS; ++dw){
        #pragma unroll
        for (int nf = 0; nf < 4; ++nf){
          int w_out = nf*16 + lo;
          int wp = w_out + dw - P;
          frag8 bx0 = {0,0,0,0,0,0,0,0}, bx1 = {0,0,0,0,0,0,0,0};
          if (wp >= 0 && wp < 64){
            int rowb = (rl*64 + wp)*128;
            int sw = (wp & 7) << 4;
            bx0 = *reinterpret_cast<const frag8*>((char*)xs + rowb + ((hi*16) ^ sw));
            bx1 = *reinterpret_cast<const frag8*>((char*)xs + rowb + ((64 + hi*16) ^ sw));
          }
          acc[nf] = MFMA(wf[dw][0], bx0, acc[nf]);
          acc[nf] = MFMA(wf[dw][1], bx1, acc[nf]);
        }
      }
    }
  }
  #pragma unroll
  for (int nf = 0; nf < 4; ++nf){
    int w = nf*16 + lo;
    #pragma unroll
    for (int r = 0; r < 4; ++r)
      outst[hsel][w][cofrag*16 + hi*4 + r] = acc[nf][r];
  }
  __syncthreads();
  {
    int hs = tid >> 7, rem = tid & 127;
    int w = rem >> 1, c16 = (rem & 1)*16;
    int cobase = (KS == 7) ? 0 : 32;
    size_t qrow = (((size_t)b << 12) + (h0 + hs)*64 + w)*64;
    #pragma unroll
    for (int g = 0; g < 2; ++g){
      int c8 = c16 + g*8;
      us8 v;
      #pragma unroll
      for (int j = 0; j < 8; ++j)
        v[j] = f2bf((outst[hs][w][c8 + j] + bias[c8 + j]) * LOG2E);
      *reinterpret_cast<us8*>(qt + qrow + cobase + c8) = v;
    }
  }
}

// ---------------- flash attention: R10 structure + native exp2 softmax ----------------
// K,V double-buffered in LDS with reg prefetch; swapped QK^T; swizzled P round-trip.
// Q pre-scaled by log2e -> P = 2^(S'-m') via bare v_exp_f32; merge in exp2 domain.
template<int NSPLIT>
__global__ __launch_bounds__(256, 2) void attn_kernel(const unsigned short* __restrict__ qt,
    const unsigned short* __restrict__ kt, const unsigned short* __restrict__ vct,
    unsigned short* __restrict__ opart, float* __restrict__ mlpart){
  constexpr int TILES = 64 / NSPLIT;
  __shared__ unsigned short kls[2][64*64];
  __shared__ unsigned short vls[2][64*64];
  __shared__ unsigned short pls[4][32*64];
  int b = blockIdx.y, half = blockIdx.z;
  int tid = threadIdx.x, lane = tid & 63, wid = tid >> 6;
  int lo = lane & 15, hi = lane >> 4;
  int q0 = blockIdx.x*128 + wid*32;
  const size_t bb = (size_t)b << 12;
  const int mtbase = half * TILES;
  const int sm = tid >> 3, sch = tid & 7;
  const int dstA = sm*128 + ((sch*16) ^ ((sm & 7) << 4));
  const int dstB = dstA + 32*128;
  char* pbase = (char*)pls[wid];
  frag8 aq[2][2];
  #pragma unroll
  for (int mf = 0; mf < 2; ++mf)
    #pragma unroll
    for (int ks = 0; ks < 2; ++ks)
      aq[mf][ks] = *reinterpret_cast<const frag8*>(
          qt + (bb + q0 + mf*16 + lo)*64 + ks*32 + 8*hi);
  f32x4 o[2][4];
  #pragma unroll
  for (int mf = 0; mf < 2; ++mf)
    #pragma unroll
    for (int f = 0; f < 4; ++f) o[mf][f] = (f32x4){0.f,0.f,0.f,0.f};
  float mr[2]  = {-1e30f, -1e30f};
  float lr[2]  = {0.f, 0.f};
  float mrT[2][4];
  #pragma unroll
  for (int mf = 0; mf < 2; ++mf)
    #pragma unroll
    for (int r = 0; r < 4; ++r) mrT[mf][r] = -1e30f;
  us8 kr0, kr1, vr0, vr1;
  {
    int mt = mtbase;
    kr0 = *reinterpret_cast<const us8*>(kt + (bb + mt*64 + sm)*64 + sch*8);
    kr1 = *reinterpret_cast<const us8*>(kt + (bb + mt*64 + sm + 32)*64 + sch*8);
    vr0 = *reinterpret_cast<const us8*>(vct + (((size_t)b*64 + sm) << 12) + mt*64 + sch*8);
    vr1 = *reinterpret_cast<const us8*>(vct + (((size_t)b*64 + sm + 32) << 12) + mt*64 + sch*8);
    *reinterpret_cast<us8*>((char*)kls[0] + dstA) = kr0;
    *reinterpret_cast<us8*>((char*)kls[0] + dstB) = kr1;
    *reinterpret_cast<us8*>((char*)vls[0] + dstA) = vr0;
    *reinterpret_cast<us8*>((char*)vls[0] + dstB) = vr1;
  }
  __syncthreads();
  int cur = 0;
  for (int t = 0; t < TILES; ++t){
    if (t < TILES-1){
      int mt = mtbase + t + 1;
      kr0 = *reinterpret_cast<const us8*>(kt + (bb + mt*64 + sm)*64 + sch*8);
      kr1 = *reinterpret_cast<const us8*>(kt + (bb + mt*64 + sm + 32)*64 + sch*8);
      vr0 = *reinterpret_cast<const us8*>(vct + (((size_t)b*64 + sm) << 12) + mt*64 + sch*8);
      vr1 = *reinterpret_cast<const us8*>(vct + (((size_t)b*64 + sm + 32) << 12) + mt*64 + sch*8);
    }
    // QK^T swapped: S^T[m][q] = K · Q   (S already scaled by log2e via Q)
    f32x4 s[2][4];
    #pragma unroll
    for (int mf = 0; mf < 2; ++mf)
      #pragma unroll
      for (int f = 0; f < 4; ++f) s[mf][f] = (f32x4){0.f,0.f,0.f,0.f};
    #pragma unroll
    for (int nf = 0; nf < 4; ++nf){
      int m = nf*16 + lo;
      int sw = (m & 7) << 4;
      frag8 b0 = *reinterpret_cast<const frag8*>((char*)kls[cur] + m*128 + ((hi*16) ^ sw));
      frag8 b1 = *reinterpret_cast<const frag8*>((char*)kls[cur] + m*128 + ((64 + hi*16) ^ sw));
      s[0][nf] = MFMA(b0, aq[0][0], s[0][nf]);
      s[0][nf] = MFMA(b1, aq[0][1], s[0][nf]);
      s[1][nf] = MFMA(b0, aq[1][0], s[1][nf]);
      s[1][nf] = MFMA(b1, aq[1][1], s[1][nf]);
    }
    // defer-max on per-lane partials (scaled domain: THR = 8*log2e)
    float pm[2];
    #pragma unroll
    for (int mf = 0; mf < 2; ++mf){
      float a0 = fmaxf(fmaxf(s[mf][0][0], s[mf][0][1]), fmaxf(s[mf][0][2], s[mf][0][3]));
      float a1 = fmaxf(fmaxf(s[mf][1][0], s[mf][1][1]), fmaxf(s[mf][1][2], s[mf][1][3]));
      float a2 = fmaxf(fmaxf(s[mf][2][0], s[mf][2][1]), fmaxf(s[mf][2][2], s[mf][2][3]));
      float a3 = fmaxf(fmaxf(s[mf][3][0], s[mf][3][1]), fmaxf(s[mf][3][2], s[mf][3][3]));
      pm[mf] = fmaxf(fmaxf(a0, a1), fmaxf(a2, a3));
    }
    float growth = fmaxf(pm[0] - mr[0], pm[1] - mr[1]);
    if (!__all(growth <= 11.5416f)){
      float rmax[2] = {pm[0], pm[1]};
      #pragma unroll
      for (int mf = 0; mf < 2; ++mf){
        rmax[mf] = fmaxf(rmax[mf], __shfl_xor(rmax[mf], 16));
        rmax[mf] = fmaxf(rmax[mf], __shfl_xor(rmax[mf], 32));
        float mn = fmaxf(mr[mf], rmax[mf]);
        lr[mf] *= EXP2(mr[mf] - mn);
        mr[mf] = mn;
      }
      #pragma unroll
      for (int mf = 0; mf < 2; ++mf)
        #pragma unroll
        for (int r = 0; r < 4; ++r){
          float mnT = __shfl(mr[mf], hi*4 + r);
          float scT = EXP2(mrT[mf][r] - mnT);
          mrT[mf][r] = mnT;
          #pragma unroll
          for (int cf = 0; cf < 4; ++cf) o[mf][cf][r] *= scT;
        }
    }
    // P = 2^(S'-m'); per-lane l partial; packed b64 P-writes
    #pragma unroll
    for (int mf = 0; mf < 2; ++mf){
      float acc = 0.f;
      #pragma unroll
      for (int nf = 0; nf < 4; ++nf){
        #pragma unroll
        for (int r = 0; r < 4; ++r){
          s[mf][nf][r] = EXP2(s[mf][nf][r] - mr[mf]);
          acc += s[mf][nf][r];
        }
        u32x2 w;
        w[0] = cvt_pk_bf16(s[mf][nf][0], s[mf][nf][1]);
        w[1] = cvt_pk_bf16(s[mf][nf][2], s[mf][nf][3]);
        *reinterpret_cast<u32x2*>(pbase + (mf*16 + lo)*128 +
            ((nf*32 + hi*8) ^ ((lo & 7) << 4))) = w;
      }
      lr[mf] += acc;
    }
    // PV: A = P (swizzled b128 rows), B = V frags from LDS
    #pragma unroll
    for (int ks = 0; ks < 2; ++ks){
      frag8 ap0 = *reinterpret_cast<const frag8*>(
          pbase + lo*128 + ((ks*64 + hi*16) ^ ((lo & 7) << 4)));
      frag8 ap1 = *reinterpret_cast<const frag8*>(
          pbase + (16 + lo)*128 + ((ks*64 + hi*16) ^ ((lo & 7) << 4)));
      #pragma unroll
      for (int cf = 0; cf < 4; ++cf){
        int c = cf*16 + lo;
        frag8 bv = *reinterpret_cast<const frag8*>(
            (char*)vls[cur] + c*128 + ((ks*64 + hi*16) ^ ((c & 7) << 4)));
        o[0][cf] = MFMA(ap0, bv, o[0][cf]);
        o[1][cf] = MFMA(ap1, bv, o[1][cf]);
      }
    }
    if (t < TILES-1){
      *reinterpret_cast<us8*>((char*)kls[cur^1] + dstA) = kr0;
      *reinterpret_cast<us8*>((char*)kls[cur^1] + dstB) = kr1;
      *reinterpret_cast<us8*>((char*)vls[cur^1] + dstA) = vr0;
      *reinterpret_cast<us8*>((char*)vls[cur^1] + dstB) = vr1;
    }
    __syncthreads();
    cur ^= 1;
  }
  #pragma unroll
  for (int mf = 0; mf < 2; ++mf){
    lr[mf] += __shfl_xor(lr[mf], 16);
    lr[mf] += __shfl_xor(lr[mf], 32);
  }
  size_t pb = ((size_t)(half*8 + b) << 12);
  #pragma unroll
  for (int mf = 0; mf < 2; ++mf){
    #pragma unroll
    for (int cf = 0; cf < 4; ++cf)
      #pragma unroll
      for (int r = 0; r < 4; ++r)
        opart[(pb + q0 + mf*16 + hi*4 + r)*64 + cf*16 + lo] = f2bf(o[mf][cf][r]);
    if (hi == 0){
      size_t idx = pb + q0 + mf*16 + lo;
      mlpart[idx*2]     = mr[mf];
      mlpart[idx*2 + 1] = lr[mf];
    }
  }
}

// ---------------- merge of the KV splits (bf16 partials, exp2 domain) ----------------
template<int NSPLIT>
__global__ __launch_bounds__(256) void merge_kernel(const unsigned short* __restrict__ opart,
    const float* __restrict__ mlpart, unsigned short* __restrict__ o1t){
  int g = blockIdx.x*256 + threadIdx.x;
  int c4 = g & 15, q = (g >> 4) & 4095, b = g >> 16;
  size_t idx[NSPLIT];
  float m[NSPLIT], l[NSPLIT];
  float M = -1e30f;
  #pragma unroll
  for (int p = 0; p < NSPLIT; ++p){
    idx[p] = ((size_t)(p*8 + b) << 12) + q;
    m[p] = mlpart[idx[p]*2];
    l[p] = mlpart[idx[p]*2 + 1];
    M = fmaxf(M, m[p]);
  }
  float denom = 0.f, w[NSPLIT];
  #pragma unroll
  for (int p = 0; p < NSPLIT; ++p){
    w[p] = EXP2(m[p] - M);
    denom += w[p] * l[p];
  }
  float inv = 1.0f / denom;
  f32x4 acc = (f32x4){0.f,0.f,0.f,0.f};
  #pragma unroll
  for (int p = 0; p < NSPLIT; ++p){
    us4 a = *reinterpret_cast<const us4*>(opart + idx[p]*64 + c4*4);
    float wp = w[p] * inv;
    #pragma unroll
    for (int j = 0; j < 4; ++j) acc[j] += wp * bf2f(a[j]);
  }
  unsigned short outv[4];
  #pragma unroll
  for (int j = 0; j < 4; ++j) outv[j] = f2bf(acc[j]);
  *reinterpret_cast<ulonglong1*>(o1t + (((size_t)b << 12) + q)*64 + c4*4) =
      *reinterpret_cast<ulonglong1*>(outv);
}

// ---------------- c1 (concat + 1x1 conv + BN + SiLU) ----------------
__global__ __launch_bounds__(256) void c1_kernel(const unsigned short* __restrict__ o1t,
    const unsigned short* __restrict__ xt, const unsigned short* __restrict__ wc1b,
    const float* __restrict__ bc1, unsigned short* __restrict__ zt){
  int b = blockIdx.y;
  int q0 = blockIdx.x*64 + (threadIdx.x >> 6)*16;
  int lane = threadIdx.x & 63, lo = lane & 15, hi = lane >> 4;
  size_t bb = (size_t)b << 12;
  f32x4 acc[16];
  #pragma unroll
  for (int nf = 0; nf < 16; ++nf) acc[nf] = (f32x4){0.f,0.f,0.f,0.f};
  #pragma unroll
  for (int ks = 0; ks < 8; ++ks){
    int ci0 = ks*32 + 8*hi;
    frag8 a;
    if (ks < 2) a = *reinterpret_cast<const frag8*>(o1t + (bb + q0 + lo)*64 + ci0);
    else        a = *reinterpret_cast<const frag8*>(xt  + (bb + q0 + lo)*256 + ci0);
    #pragma unroll
    for (int nf = 0; nf < 16; ++nf){
      frag8 w = *reinterpret_cast<const frag8*>(wc1b + (nf*16 + lo)*256 + ci0);
      acc[nf] = MFMA(a, w, acc[nf]);
    }
  }
  #pragma unroll
  for (int nf = 0; nf < 16; ++nf){
    int co = nf*16 + lo;
    float bias = bc1[co];
    #pragma unroll
    for (int r = 0; r < 4; ++r){
      float y = acc[nf][r] + bias;
      y = y / (1.0f + __expf(-y));
      zt[(bb + q0 + hi*4 + r)*256 + co] = f2bf(y);
    }
  }
}

// ---------------- c2 (1x1 conv, weight-stationary, fp32 NCHW out) ----------------
__global__ __launch_bounds__(256) void c2_kernel(const unsigned short* __restrict__ zt,
    const unsigned short* __restrict__ wc2b, const float* __restrict__ bc2,
    float* __restrict__ out){
  int b = blockIdx.y;
  int q0 = blockIdx.x*128 + (threadIdx.x >> 6)*32;
  int lane = threadIdx.x & 63, lo = lane & 15, hi = lane >> 4;
  size_t bb = (size_t)b << 12;
  f32x4 acc[16][2];
  #pragma unroll
  for (int mf = 0; mf < 16; ++mf){
    acc[mf][0] = (f32x4){0.f,0.f,0.f,0.f};
    acc[mf][1] = (f32x4){0.f,0.f,0.f,0.f};
  }
  #pragma unroll
  for (int ks = 0; ks < 8; ++ks){
    int ci0 = ks*32 + 8*hi;
    frag8 bz0 = *reinterpret_cast<const frag8*>(zt + (bb + q0 + lo)*256 + ci0);
    frag8 bz1 = *reinterpret_cast<const frag8*>(zt + (bb + q0 + 16 + lo)*256 + ci0);
    #pragma unroll
    for (int mf = 0; mf < 16; ++mf){
      frag8 aw = *reinterpret_cast<const frag8*>(wc2b + (mf*16 + lo)*256 + ci0);
      acc[mf][0] = MFMA(aw, bz0, acc[mf][0]);
      acc[mf][1] = MFMA(aw, bz1, acc[mf][1]);
    }
  }
  #pragma unroll
  for (int mf = 0; mf < 16; ++mf){
    #pragma unroll
    for (int r = 0; r < 4; ++r){
      int co = mf*16 + hi*4 + r;
      float bias = bc2[co];
      float* op = out + (((size_t)b*256 + co) << 12) + q0 + lo;
      op[0]  = acc[mf][0][r] + bias;
      op[16] = acc[mf][1][r] + bias;
    }
  }
}

// ---------------- launch ----------------
extern "C" void kernel_launch(void* const* d_in, const int* in_sizes, int n_in,
                              void* d_out, int out_size, void* d_ws, size_t ws_size,
                              hipStream_t stream){
  const float* x    = (const float*)d_in[0];
  const float* wdw1 = (const float*)d_in[1];
  const float* bdw1 = (const float*)d_in[2];
  const float* wdw2 = (const float*)d_in[3];
  const float* bdw2 = (const float*)d_in[4];
  const float* wk   = (const float*)d_in[5];
  const float* bk   = (const float*)d_in[6];
  const float* wv   = (const float*)d_in[7];
  const float* bv   = (const float*)d_in[8];
  const float* wc1  = (const float*)d_in[9];
  const float* bng  = (const float*)d_in[10];
  const float* bnb  = (const float*)d_in[11];
  const float* bnm  = (const float*)d_in[12];
  const float* bnv  = (const float*)d_in[13];
  const float* wc2  = (const float*)d_in[14];
  const float* bc2  = (const float*)d_in[15];
  char* ws = (char*)d_ws;
  unsigned short* xt   = (unsigned short*)(ws + OFF_XT);
  unsigned short* ktp  = (unsigned short*)(ws + OFF_KT);
  unsigned short* vct  = (unsigned short*)(ws + OFF_VCT);
  unsigned short* qtp  = (unsigned short*)(ws + OFF_QT);
  unsigned short* o1t  = (unsigned short*)(ws + OFF_O1T);
  unsigned short* zt   = (unsigned short*)(ws + OFF_ZT);
  unsigned short* wq7  = (unsigned short*)(ws + OFF_WQ7);
  unsigned short* wq11 = (unsigned short*)(ws + OFF_WQ11);
  unsigned short* wc1b = (unsigned short*)(ws + OFF_WC1);
  unsigned short* wc2b = (unsigned short*)(ws + OFF_WC2);
  float*          bc1  = (float*)(ws + OFF_BC1);
  unsigned short* wkb  = (unsigned short*)(ws + OFF_WKB);
  unsigned short* wvb  = (unsigned short*)(ws + OFF_WVB);
  unsigned short* opart = (unsigned short*)(ws + OFF_ZT);  // bf16 partials alias zt
  const bool big = (ws_size >= WS_NEED4);
  float*          mlp   = (float*)(ws + (big ? OFF_ML4 : OFF_ML2));

  prep_weights_kernel<<<1904, 256, 0, stream>>>(wdw1, wdw2, wc1, bng, bnb, bnm, bnv,
                                                wc2, wk, wv, wq7, wq11, wc1b, wc2b,
                                                bc1, wkb, wvb);
  prep_x_kernel<<<dim3(128, 4), 256, 0, stream>>>(x, xt);
  kv_kernel<<<1024, 256, 0, stream>>>(xt, wkb, wvb, bk, bv, ktp, vct);
  conv_q_kernel<7><<<dim3(32, 8), 256, 0, stream>>>(xt, wq7, bdw1, qtp);
  conv_q_kernel<11><<<dim3(32, 8), 256, 0, stream>>>(xt, wq11, bdw2, qtp);
  if (big){
    attn_kernel<4><<<dim3(32, 8, 4), 256, 0, stream>>>(qtp, ktp, vct, opart, mlp);
    merge_kernel<4><<<2048, 256, 0, stream>>>(opart, mlp, o1t);
  } else {
    attn_kernel<2><<<dim3(32, 8, 2), 256, 0, stream>>>(qtp, ktp, vct, opart, mlp);
    merge_kernel<2><<<2048, 256, 0, stream>>>(opart, mlp, o1t);
  }
  c1_kernel<<<dim3(64, 8), 256, 0, stream>>>(o1t, xt, wc1b, bc1, zt);
  c2_kernel<<<dim3(32, 8), 256, 0, stream>>>(zt, wc2b, bc2, (float*)d_out);
}

// Round 15
// 220.133 us; speedup vs baseline: 1.1897x; 1.0470x over previous
//
#include <hip/hip_runtime.h>

typedef __attribute__((ext_vector_type(8))) short frag8;
typedef __attribute__((ext_vector_type(4))) float f32x4;
typedef __attribute__((ext_vector_type(8))) unsigned short us8;
typedef __attribute__((ext_vector_type(4))) unsigned short us4;
typedef __attribute__((ext_vector_type(2))) unsigned int u32x2;

#define MFMA(a,b,c) __builtin_amdgcn_mfma_f32_16x16x32_bf16((a),(b),(c),0,0,0)
#define LOG2E 1.44269504f
#define EXP2(x) __builtin_amdgcn_exp2f(x)   // bare v_exp_f32 (computes 2^x)

__device__ __forceinline__ unsigned short f2bf(float f){
  unsigned int u = __builtin_bit_cast(unsigned int, f);
  u += 0x7fffu + ((u >> 16) & 1u);
  return (unsigned short)(u >> 16);
}

__device__ __forceinline__ float bf2f(unsigned short h){
  unsigned int u = ((unsigned int)h) << 16;
  return __builtin_bit_cast(float, u);
}

__device__ __forceinline__ unsigned int cvt_pk_bf16(float a, float b){
  unsigned int r;
  asm volatile("v_cvt_pk_bf16_f32 %0, %1, %2" : "=v"(r) : "v"(a), "v"(b));
  return r;
}

// ---------------- workspace layout (bytes) ----------------
#define OFF_XT   ((size_t)0)            // [8][4096][256] bf16 = 16777216
#define OFF_KT   ((size_t)16777216)     // [8][4096][64]  bf16 = 4194304
#define OFF_VCT  ((size_t)20971520)     // [8][64][4096]  bf16 = 4194304
#define OFF_QT   ((size_t)25165824)     // [8][4096][64]  bf16 = 4194304
#define OFF_O1T  ((size_t)29360128)     // [8][4096][64]  bf16 = 4194304 (unused now)
#define OFF_ZT   ((size_t)33554432)     // [8][4096][256] bf16 = 16777216
                                        // attn O-partials [4][8][4096][64] bf16 alias (exact fit)
#define OFF_WQ7  ((size_t)50331648)     // [49][32][64]  bf16 = 200704
#define OFF_WQ11 ((size_t)50532352)     // [121][32][64] bf16 = 495616
#define OFF_WC1  ((size_t)51027968)     // [256][256] bf16 = 131072
#define OFF_WC2  ((size_t)51159040)     // [256][256] bf16 = 131072
#define OFF_BC1  ((size_t)51290112)     // [256] f32 = 1024
#define OFF_WKB  ((size_t)51291136)     // [64][64] bf16 = 8192
#define OFF_WVB  ((size_t)51299328)     // [64][64] bf16 = 8192  (ends 51307520)
#define OFF_ML2  OFF_WQ7                // split-2 ml [2][8][4096][2] f32 = 524288
#define OFF_ML4  ((size_t)51307520)     // split-4 ml [4][8][4096][2] f32 = 1048576
#define WS_NEED4 ((size_t)(OFF_ML4 + 1048576))   // 52356096

// ---------------- prep: weights ----------------
__global__ __launch_bounds__(256) void prep_weights_kernel(
    const float* __restrict__ wdw1, const float* __restrict__ wdw2,
    const float* __restrict__ wc1, const float* __restrict__ bng,
    const float* __restrict__ bnb, const float* __restrict__ bnm,
    const float* __restrict__ bnv, const float* __restrict__ wc2,
    const float* __restrict__ wk, const float* __restrict__ wv,
    unsigned short* __restrict__ wq7, unsigned short* __restrict__ wq11,
    unsigned short* __restrict__ wc1b, unsigned short* __restrict__ wc2b,
    float* __restrict__ bc1, unsigned short* __restrict__ wkb,
    unsigned short* __restrict__ wvb){
  int i = blockIdx.x*256 + threadIdx.x;
  if (i < 100352){
    int o = i >> 11, rem = i & 2047;
    int co = rem >> 6, ci = rem & 63;
    int kh = o / 7, kw = o % 7;
    wq7[i] = f2bf(wdw1[(co*64 + ci)*49 + kh*7 + kw]);
  } else if (i < 348160){
    int j = i - 100352;
    int o = j >> 11, rem = j & 2047;
    int co = rem >> 6, ci = rem & 63;
    int kh = o / 11, kw = o % 11;
    wq11[j] = f2bf(wdw2[(co*64 + ci)*121 + kh*11 + kw]);
  } else if (i < 413696){
    int j = i - 348160;
    int co = j >> 8;
    float a = bng[co] * rsqrtf(bnv[co] + 1e-5f);
    wc1b[j] = f2bf(wc1[j] * a);
    if ((j & 255) == 0) bc1[co] = bnb[co] - bnm[co]*a;
  } else if (i < 479232){
    int j = i - 413696;
    wc2b[j] = f2bf(wc2[j]);
  } else if (i < 483328){
    int j = i - 479232;
    wkb[j] = f2bf(wk[j]);
  } else if (i < 487424){
    int j = i - 483328;
    wvb[j] = f2bf(wv[j]);
  }
}

// ---------------- prep: transpose x (NCHW f32 -> [b][n][c] bf16) ----------------
__global__ __launch_bounds__(256) void prep_x_kernel(const float* __restrict__ x,
                                                     unsigned short* __restrict__ xt){
  int g = blockIdx.x*256 + threadIdx.x;
  int b = g >> 12, n = g & 4095;
  int c0base = blockIdx.y * 64;
  const float* xp = x + (((size_t)b*256) << 12) + n;
  unsigned short* op = xt + (size_t)g*256;
  for (int c0 = c0base; c0 < c0base + 64; c0 += 8){
    us8 v;
    #pragma unroll
    for (int j = 0; j < 8; ++j) v[j] = f2bf(xp[(size_t)(c0+j) << 12]);
    *reinterpret_cast<us8*>(op + c0) = v;
  }
}

// ---------------- k / v  (1x1 convs via MFMA) ----------------
__global__ __launch_bounds__(256) void kv_kernel(const unsigned short* __restrict__ xt,
    const unsigned short* __restrict__ wkb, const unsigned short* __restrict__ wvb,
    const float* __restrict__ bk, const float* __restrict__ bv,
    unsigned short* __restrict__ kt, unsigned short* __restrict__ vct){
  int gid = blockIdx.x;
  int part = gid >> 9, t = gid & 511;
  int b = t >> 6, tile = t & 63;
  int lane = threadIdx.x & 63, wid = threadIdx.x >> 6;
  int lo = lane & 15, hi = lane >> 4;
  int n0 = tile*64 + wid*16;
  size_t bb = (size_t)b << 12;
  f32x4 acc[4];
  #pragma unroll
  for (int f = 0; f < 4; ++f) acc[f] = (f32x4){0.f,0.f,0.f,0.f};
  frag8 x0 = *reinterpret_cast<const frag8*>(xt + (bb + n0 + lo)*256 + 8*hi);
  frag8 x1 = *reinterpret_cast<const frag8*>(xt + (bb + n0 + lo)*256 + 32 + 8*hi);
  if (part == 0){
    #pragma unroll
    for (int nf = 0; nf < 4; ++nf){
      frag8 w0 = *reinterpret_cast<const frag8*>(wkb + (nf*16 + lo)*64 + 8*hi);
      frag8 w1 = *reinterpret_cast<const frag8*>(wkb + (nf*16 + lo)*64 + 32 + 8*hi);
      acc[nf] = MFMA(x0, w0, acc[nf]);
      acc[nf] = MFMA(x1, w1, acc[nf]);
    }
    #pragma unroll
    for (int nf = 0; nf < 4; ++nf){
      int co = nf*16 + lo;
      float bias = bk[co];
      #pragma unroll
      for (int r = 0; r < 4; ++r)
        kt[(bb + n0 + hi*4 + r)*64 + co] = f2bf(acc[nf][r] + bias);
    }
  } else {
    #pragma unroll
    for (int mf = 0; mf < 4; ++mf){
      frag8 w0 = *reinterpret_cast<const frag8*>(wvb + (mf*16 + lo)*64 + 8*hi);
      frag8 w1 = *reinterpret_cast<const frag8*>(wvb + (mf*16 + lo)*64 + 32 + 8*hi);
      acc[mf] = MFMA(w0, x0, acc[mf]);
      acc[mf] = MFMA(w1, x1, acc[mf]);
    }
    #pragma unroll
    for (int mf = 0; mf < 4; ++mf){
      #pragma unroll
      for (int r = 0; r < 4; ++r){
        int c = mf*16 + hi*4 + r;
        vct[(((size_t)b*64 + c) << 12) + n0 + lo] = f2bf(acc[mf][r] + bv[c]);
      }
    }
  }
}

// ---------------- Q conv body (h-pair weight-stationary implicit GEMM) ----------------
// Epilogue scales Q by log2(e) so attention can use the bare v_exp_f32 (2^x).
template<int KS>
__device__ __forceinline__ void conv_body(const unsigned short* __restrict__ xt,
    const unsigned short* __restrict__ wq, const float* __restrict__ bias,
    unsigned short* __restrict__ qt, int h0, int b,
    unsigned short* xs, float* outst /* [2][64][33] */){
  constexpr int P = KS/2;
  constexpr int NR = (KS+1)/2;
  int tid = threadIdx.x, lane = tid & 63, wid = tid >> 6;
  int lo = lane & 15, hi = lane >> 4;
  int cofrag = wid & 1, hsel = wid >> 1;
  int h = h0 + hsel;
  f32x4 acc[4];
  #pragma unroll
  for (int nf = 0; nf < 4; ++nf) acc[nf] = (f32x4){0.f,0.f,0.f,0.f};
  const size_t xbase = ((size_t)b << 12) * 256;
  #pragma unroll
  for (int pass = 0; pass < 2; ++pass){
    const int srcBase = h0 - P + pass*NR;
    if (pass) __syncthreads();
    for (int idx = tid; idx < NR*512; idx += 256){
      int rl = idx >> 9, w = (idx >> 3) & 63, ch = idx & 7;
      int sr = srcBase + rl;
      us8 v = {0,0,0,0,0,0,0,0};
      if (sr >= 0 && sr < 64)
        v = *reinterpret_cast<const us8*>(xt + xbase + (size_t)(sr*64 + w)*256 + ch*8);
      int byte = (rl*64 + w)*128 + ((ch*16) ^ ((w & 7) << 4));
      *reinterpret_cast<us8*>((char*)xs + byte) = v;
    }
    __syncthreads();
    for (int rl = 0; rl < NR; ++rl){
      int dh = srcBase + rl - h + P;
      if (dh < 0 || dh >= KS) continue;
      frag8 wf[KS][2];
      int off0 = dh*KS;
      #pragma unroll
      for (int dw = 0; dw < KS; ++dw){
        #pragma unroll
        for (int ks = 0; ks < 2; ++ks)
          wf[dw][ks] = *reinterpret_cast<const frag8*>(
              wq + (size_t)(off0+dw)*2048 + (cofrag*16 + lo)*64 + ks*32 + 8*hi);
      }
      #pragma unroll
      for (int dw = 0; dw < KS; ++dw){
        #pragma unroll
        for (int nf = 0; nf < 4; ++nf){
          int w_out = nf*16 + lo;
          int wp = w_out + dw - P;
          frag8 bx0 = {0,0,0,0,0,0,0,0}, bx1 = {0,0,0,0,0,0,0,0};
          if (wp >= 0 && wp < 64){
            int rowb = (rl*64 + wp)*128;
            int sw = (wp & 7) << 4;
            bx0 = *reinterpret_cast<const frag8*>((char*)xs + rowb + ((hi*16) ^ sw));
            bx1 = *reinterpret_cast<const frag8*>((char*)xs + rowb + ((64 + hi*16) ^ sw));
          }
          acc[nf] = MFMA(wf[dw][0], bx0, acc[nf]);
          acc[nf] = MFMA(wf[dw][1], bx1, acc[nf]);
        }
      }
    }
  }
  #pragma unroll
  for (int nf = 0; nf < 4; ++nf){
    int w = nf*16 + lo;
    #pragma unroll
    for (int r = 0; r < 4; ++r)
      outst[(hsel*64 + w)*33 + cofrag*16 + hi*4 + r] = acc[nf][r];
  }
  __syncthreads();
  {
    int hs = tid >> 7, rem = tid & 127;
    int w = rem >> 1, c16 = (rem & 1)*16;
    int cobase = (KS == 7) ? 0 : 32;
    size_t qrow = (((size_t)b << 12) + (h0 + hs)*64 + w)*64;
    #pragma unroll
    for (int g = 0; g < 2; ++g){
      int c8 = c16 + g*8;
      us8 v;
      #pragma unroll
      for (int j = 0; j < 8; ++j)
        v[j] = f2bf((outst[(hs*64 + w)*33 + c8 + j] + bias[c8 + j]) * LOG2E);
      *reinterpret_cast<us8*>(qt + qrow + cobase + c8) = v;
    }
  }
}

// Combined conv7+conv11 launch: 512 blocks (2/CU) instead of 2x256 (1/CU each).
__global__ __launch_bounds__(256) void conv_q_both_kernel(
    const unsigned short* __restrict__ xt,
    const unsigned short* __restrict__ wq7, const unsigned short* __restrict__ wq11,
    const float* __restrict__ b7, const float* __restrict__ b11,
    unsigned short* __restrict__ qt){
  __shared__ unsigned short xs[6*64*64];     // max NR=6 (KS=11)
  __shared__ float outst[2*64*33];
  int bx = blockIdx.x, b = blockIdx.y;
  if (bx < 32) conv_body<7>(xt, wq7, b7, qt, bx*2, b, xs, outst);
  else         conv_body<11>(xt, wq11, b11, qt, (bx-32)*2, b, xs, outst);
}

// ---------------- flash attention: R10 structure + native exp2 softmax ----------------
template<int NSPLIT>
__global__ __launch_bounds__(256, 2) void attn_kernel(const unsigned short* __restrict__ qt,
    const unsigned short* __restrict__ kt, const unsigned short* __restrict__ vct,
    unsigned short* __restrict__ opart, float* __restrict__ mlpart){
  constexpr int TILES = 64 / NSPLIT;
  __shared__ unsigned short kls[2][64*64];
  __shared__ unsigned short vls[2][64*64];
  __shared__ unsigned short pls[4][32*64];
  int b = blockIdx.y, half = blockIdx.z;
  int tid = threadIdx.x, lane = tid & 63, wid = tid >> 6;
  int lo = lane & 15, hi = lane >> 4;
  int q0 = blockIdx.x*128 + wid*32;
  const size_t bb = (size_t)b << 12;
  const int mtbase = half * TILES;
  const int sm = tid >> 3, sch = tid & 7;
  const int dstA = sm*128 + ((sch*16) ^ ((sm & 7) << 4));
  const int dstB = dstA + 32*128;
  char* pbase = (char*)pls[wid];
  frag8 aq[2][2];
  #pragma unroll
  for (int mf = 0; mf < 2; ++mf)
    #pragma unroll
    for (int ks = 0; ks < 2; ++ks)
      aq[mf][ks] = *reinterpret_cast<const frag8*>(
          qt + (bb + q0 + mf*16 + lo)*64 + ks*32 + 8*hi);
  f32x4 o[2][4];
  #pragma unroll
  for (int mf = 0; mf < 2; ++mf)
    #pragma unroll
    for (int f = 0; f < 4; ++f) o[mf][f] = (f32x4){0.f,0.f,0.f,0.f};
  float mr[2]  = {-1e30f, -1e30f};
  float lr[2]  = {0.f, 0.f};
  float mrT[2][4];
  #pragma unroll
  for (int mf = 0; mf < 2; ++mf)
    #pragma unroll
    for (int r = 0; r < 4; ++r) mrT[mf][r] = -1e30f;
  us8 kr0, kr1, vr0, vr1;
  {
    int mt = mtbase;
    kr0 = *reinterpret_cast<const us8*>(kt + (bb + mt*64 + sm)*64 + sch*8);
    kr1 = *reinterpret_cast<const us8*>(kt + (bb + mt*64 + sm + 32)*64 + sch*8);
    vr0 = *reinterpret_cast<const us8*>(vct + (((size_t)b*64 + sm) << 12) + mt*64 + sch*8);
    vr1 = *reinterpret_cast<const us8*>(vct + (((size_t)b*64 + sm + 32) << 12) + mt*64 + sch*8);
    *reinterpret_cast<us8*>((char*)kls[0] + dstA) = kr0;
    *reinterpret_cast<us8*>((char*)kls[0] + dstB) = kr1;
    *reinterpret_cast<us8*>((char*)vls[0] + dstA) = vr0;
    *reinterpret_cast<us8*>((char*)vls[0] + dstB) = vr1;
  }
  __syncthreads();
  int cur = 0;
  for (int t = 0; t < TILES; ++t){
    if (t < TILES-1){
      int mt = mtbase + t + 1;
      kr0 = *reinterpret_cast<const us8*>(kt + (bb + mt*64 + sm)*64 + sch*8);
      kr1 = *reinterpret_cast<const us8*>(kt + (bb + mt*64 + sm + 32)*64 + sch*8);
      vr0 = *reinterpret_cast<const us8*>(vct + (((size_t)b*64 + sm) << 12) + mt*64 + sch*8);
      vr1 = *reinterpret_cast<const us8*>(vct + (((size_t)b*64 + sm + 32) << 12) + mt*64 + sch*8);
    }
    // QK^T swapped: S^T[m][q] = K · Q   (S already scaled by log2e via Q)
    f32x4 s[2][4];
    #pragma unroll
    for (int mf = 0; mf < 2; ++mf)
      #pragma unroll
      for (int f = 0; f < 4; ++f) s[mf][f] = (f32x4){0.f,0.f,0.f,0.f};
    #pragma unroll
    for (int nf = 0; nf < 4; ++nf){
      int m = nf*16 + lo;
      int sw = (m & 7) << 4;
      frag8 b0 = *reinterpret_cast<const frag8*>((char*)kls[cur] + m*128 + ((hi*16) ^ sw));
      frag8 b1 = *reinterpret_cast<const frag8*>((char*)kls[cur] + m*128 + ((64 + hi*16) ^ sw));
      s[0][nf] = MFMA(b0, aq[0][0], s[0][nf]);
      s[0][nf] = MFMA(b1, aq[0][1], s[0][nf]);
      s[1][nf] = MFMA(b0, aq[1][0], s[1][nf]);
      s[1][nf] = MFMA(b1, aq[1][1], s[1][nf]);
    }
    // defer-max on per-lane partials (scaled domain: THR = 8*log2e)
    float pm[2];
    #pragma unroll
    for (int mf = 0; mf < 2; ++mf){
      float a0 = fmaxf(fmaxf(s[mf][0][0], s[mf][0][1]), fmaxf(s[mf][0][2], s[mf][0][3]));
      float a1 = fmaxf(fmaxf(s[mf][1][0], s[mf][1][1]), fmaxf(s[mf][1][2], s[mf][1][3]));
      float a2 = fmaxf(fmaxf(s[mf][2][0], s[mf][2][1]), fmaxf(s[mf][2][2], s[mf][2][3]));
      float a3 = fmaxf(fmaxf(s[mf][3][0], s[mf][3][1]), fmaxf(s[mf][3][2], s[mf][3][3]));
      pm[mf] = fmaxf(fmaxf(a0, a1), fmaxf(a2, a3));
    }
    float growth = fmaxf(pm[0] - mr[0], pm[1] - mr[1]);
    if (!__all(growth <= 11.5416f)){
      float rmax[2] = {pm[0], pm[1]};
      #pragma unroll
      for (int mf = 0; mf < 2; ++mf){
        rmax[mf] = fmaxf(rmax[mf], __shfl_xor(rmax[mf], 16));
        rmax[mf] = fmaxf(rmax[mf], __shfl_xor(rmax[mf], 32));
        float mn = fmaxf(mr[mf], rmax[mf]);
        lr[mf] *= EXP2(mr[mf] - mn);
        mr[mf] = mn;
      }
      #pragma unroll
      for (int mf = 0; mf < 2; ++mf)
        #pragma unroll
        for (int r = 0; r < 4; ++r){
          float mnT = __shfl(mr[mf], hi*4 + r);
          float scT = EXP2(mrT[mf][r] - mnT);
          mrT[mf][r] = mnT;
          #pragma unroll
          for (int cf = 0; cf < 4; ++cf) o[mf][cf][r] *= scT;
        }
    }
    // P = 2^(S'-m'); per-lane l partial; packed b64 P-writes
    #pragma unroll
    for (int mf = 0; mf < 2; ++mf){
      float acc = 0.f;
      #pragma unroll
      for (int nf = 0; nf < 4; ++nf){
        #pragma unroll
        for (int r = 0; r < 4; ++r){
          s[mf][nf][r] = EXP2(s[mf][nf][r] - mr[mf]);
          acc += s[mf][nf][r];
        }
        u32x2 w;
        w[0] = cvt_pk_bf16(s[mf][nf][0], s[mf][nf][1]);
        w[1] = cvt_pk_bf16(s[mf][nf][2], s[mf][nf][3]);
        *reinterpret_cast<u32x2*>(pbase + (mf*16 + lo)*128 +
            ((nf*32 + hi*8) ^ ((lo & 7) << 4))) = w;
      }
      lr[mf] += acc;
    }
    // PV: A = P (swizzled b128 rows), B = V frags from LDS
    #pragma unroll
    for (int ks = 0; ks < 2; ++ks){
      frag8 ap0 = *reinterpret_cast<const frag8*>(
          pbase + lo*128 + ((ks*64 + hi*16) ^ ((lo & 7) << 4)));
      frag8 ap1 = *reinterpret_cast<const frag8*>(
          pbase + (16 + lo)*128 + ((ks*64 + hi*16) ^ ((lo & 7) << 4)));
      #pragma unroll
      for (int cf = 0; cf < 4; ++cf){
        int c = cf*16 + lo;
        frag8 bv = *reinterpret_cast<const frag8*>(
            (char*)vls[cur] + c*128 + ((ks*64 + hi*16) ^ ((c & 7) << 4)));
        o[0][cf] = MFMA(ap0, bv, o[0][cf]);
        o[1][cf] = MFMA(ap1, bv, o[1][cf]);
      }
    }
    if (t < TILES-1){
      *reinterpret_cast<us8*>((char*)kls[cur^1] + dstA) = kr0;
      *reinterpret_cast<us8*>((char*)kls[cur^1] + dstB) = kr1;
      *reinterpret_cast<us8*>((char*)vls[cur^1] + dstA) = vr0;
      *reinterpret_cast<us8*>((char*)vls[cur^1] + dstB) = vr1;
    }
    __syncthreads();
    cur ^= 1;
  }
  #pragma unroll
  for (int mf = 0; mf < 2; ++mf){
    lr[mf] += __shfl_xor(lr[mf], 16);
    lr[mf] += __shfl_xor(lr[mf], 32);
  }
  size_t pb = ((size_t)(half*8 + b) << 12);
  #pragma unroll
  for (int mf = 0; mf < 2; ++mf){
    #pragma unroll
    for (int cf = 0; cf < 4; ++cf)
      #pragma unroll
      for (int r = 0; r < 4; ++r)
        opart[(pb + q0 + mf*16 + hi*4 + r)*64 + cf*16 + lo] = f2bf(o[mf][cf][r]);
    if (hi == 0){
      size_t idx = pb + q0 + mf*16 + lo;
      mlpart[idx*2]     = mr[mf];
      mlpart[idx*2 + 1] = lr[mf];
    }
  }
}

// ---------------- c1 with fused split-merge (concat + 1x1 conv + BN + SiLU) -----------
// Per lane (row q = q0+lo): merge weights once, build ks<2 A-frags from the NSPLIT
// bf16 O-partials directly (no merge kernel, no o1t round-trip).
template<int NSPLIT>
__global__ __launch_bounds__(256) void c1m_kernel(const unsigned short* __restrict__ opart,
    const float* __restrict__ mlpart, const unsigned short* __restrict__ xt,
    const unsigned short* __restrict__ wc1b, const float* __restrict__ bc1,
    unsigned short* __restrict__ zt){
  int b = blockIdx.y;
  int q0 = blockIdx.x*64 + (threadIdx.x >> 6)*16;
  int lane = threadIdx.x & 63, lo = lane & 15, hi = lane >> 4;
  size_t bb = (size_t)b << 12;
  int q = q0 + lo;
  // merge weights for row q
  size_t idxp[NSPLIT];
  float m[NSPLIT], l[NSPLIT];
  float M = -1e30f;
  #pragma unroll
  for (int p = 0; p < NSPLIT; ++p){
    idxp[p] = ((size_t)(p*8 + b) << 12) + q;
    m[p] = mlpart[idxp[p]*2];
    l[p] = mlpart[idxp[p]*2 + 1];
    M = fmaxf(M, m[p]);
  }
  float denom = 0.f, wp[NSPLIT];
  #pragma unroll
  for (int p = 0; p < NSPLIT; ++p){
    wp[p] = EXP2(m[p] - M);
    denom += wp[p] * l[p];
  }
  float inv = 1.0f / denom;
  #pragma unroll
  for (int p = 0; p < NSPLIT; ++p) wp[p] *= inv;
  f32x4 acc[16];
  #pragma unroll
  for (int nf = 0; nf < 16; ++nf) acc[nf] = (f32x4){0.f,0.f,0.f,0.f};
  #pragma unroll
  for (int ks = 0; ks < 8; ++ks){
    int ci0 = ks*32 + 8*hi;
    frag8 a;
    if (ks < 2){
      float av[8] = {0.f,0.f,0.f,0.f,0.f,0.f,0.f,0.f};
      #pragma unroll
      for (int p = 0; p < NSPLIT; ++p){
        us8 ap = *reinterpret_cast<const us8*>(opart + idxp[p]*64 + ci0);
        #pragma unroll
        for (int j = 0; j < 8; ++j) av[j] += wp[p] * bf2f(ap[j]);
      }
      union { unsigned u[4]; frag8 f; } pk;
      #pragma unroll
      for (int j = 0; j < 4; ++j) pk.u[j] = cvt_pk_bf16(av[2*j], av[2*j+1]);
      a = pk.f;
    } else {
      a = *reinterpret_cast<const frag8*>(xt + (bb + q0 + lo)*256 + ci0);
    }
    #pragma unroll
    for (int nf = 0; nf < 16; ++nf){
      frag8 w = *reinterpret_cast<const frag8*>(wc1b + (nf*16 + lo)*256 + ci0);
      acc[nf] = MFMA(a, w, acc[nf]);
    }
  }
  #pragma unroll
  for (int nf = 0; nf < 16; ++nf){
    int co = nf*16 + lo;
    float bias = bc1[co];
    #pragma unroll
    for (int r = 0; r < 4; ++r){
      float y = acc[nf][r] + bias;
      y = y / (1.0f + __expf(-y));
      zt[(bb + q0 + hi*4 + r)*256 + co] = f2bf(y);
    }
  }
}

// ---------------- c2 (1x1 conv, weight-stationary, fp32 NCHW out) ----------------
__global__ __launch_bounds__(256) void c2_kernel(const unsigned short* __restrict__ zt,
    const unsigned short* __restrict__ wc2b, const float* __restrict__ bc2,
    float* __restrict__ out){
  int b = blockIdx.y;
  int q0 = blockIdx.x*128 + (threadIdx.x >> 6)*32;
  int lane = threadIdx.x & 63, lo = lane & 15, hi = lane >> 4;
  size_t bb = (size_t)b << 12;
  f32x4 acc[16][2];
  #pragma unroll
  for (int mf = 0; mf < 16; ++mf){
    acc[mf][0] = (f32x4){0.f,0.f,0.f,0.f};
    acc[mf][1] = (f32x4){0.f,0.f,0.f,0.f};
  }
  #pragma unroll
  for (int ks = 0; ks < 8; ++ks){
    int ci0 = ks*32 + 8*hi;
    frag8 bz0 = *reinterpret_cast<const frag8*>(zt + (bb + q0 + lo)*256 + ci0);
    frag8 bz1 = *reinterpret_cast<const frag8*>(zt + (bb + q0 + 16 + lo)*256 + ci0);
    #pragma unroll
    for (int mf = 0; mf < 16; ++mf){
      frag8 aw = *reinterpret_cast<const frag8*>(wc2b + (mf*16 + lo)*256 + ci0);
      acc[mf][0] = MFMA(aw, bz0, acc[mf][0]);
      acc[mf][1] = MFMA(aw, bz1, acc[mf][1]);
    }
  }
  #pragma unroll
  for (int mf = 0; mf < 16; ++mf){
    #pragma unroll
    for (int r = 0; r < 4; ++r){
      int co = mf*16 + hi*4 + r;
      float bias = bc2[co];
      float* op = out + (((size_t)b*256 + co) << 12) + q0 + lo;
      op[0]  = acc[mf][0][r] + bias;
      op[16] = acc[mf][1][r] + bias;
    }
  }
}

// ---------------- launch ----------------
extern "C" void kernel_launch(void* const* d_in, const int* in_sizes, int n_in,
                              void* d_out, int out_size, void* d_ws, size_t ws_size,
                              hipStream_t stream){
  const float* x    = (const float*)d_in[0];
  const float* wdw1 = (const float*)d_in[1];
  const float* bdw1 = (const float*)d_in[2];
  const float* wdw2 = (const float*)d_in[3];
  const float* bdw2 = (const float*)d_in[4];
  const float* wk   = (const float*)d_in[5];
  const float* bk   = (const float*)d_in[6];
  const float* wv   = (const float*)d_in[7];
  const float* bv   = (const float*)d_in[8];
  const float* wc1  = (const float*)d_in[9];
  const float* bng  = (const float*)d_in[10];
  const float* bnb  = (const float*)d_in[11];
  const float* bnm  = (const float*)d_in[12];
  const float* bnv  = (const float*)d_in[13];
  const float* wc2  = (const float*)d_in[14];
  const float* bc2  = (const float*)d_in[15];
  char* ws = (char*)d_ws;
  unsigned short* xt   = (unsigned short*)(ws + OFF_XT);
  unsigned short* ktp  = (unsigned short*)(ws + OFF_KT);
  unsigned short* vct  = (unsigned short*)(ws + OFF_VCT);
  unsigned short* qtp  = (unsigned short*)(ws + OFF_QT);
  unsigned short* zt   = (unsigned short*)(ws + OFF_ZT);
  unsigned short* wq7  = (unsigned short*)(ws + OFF_WQ7);
  unsigned short* wq11 = (unsigned short*)(ws + OFF_WQ11);
  unsigned short* wc1b = (unsigned short*)(ws + OFF_WC1);
  unsigned short* wc2b = (unsigned short*)(ws + OFF_WC2);
  float*          bc1  = (float*)(ws + OFF_BC1);
  unsigned short* wkb  = (unsigned short*)(ws + OFF_WKB);
  unsigned short* wvb  = (unsigned short*)(ws + OFF_WVB);
  unsigned short* opart = (unsigned short*)(ws + OFF_ZT);  // bf16 partials alias zt
  const bool big = (ws_size >= WS_NEED4);
  float*          mlp   = (float*)(ws + (big ? OFF_ML4 : OFF_ML2));
  // NOTE: c1m reads opart (aliasing zt) and writes zt rows for the SAME q it read —
  // but opart rows live at OFF_ZT..+16MB and zt writes land at identical byte range.
  // Write of zt[q][co] overwrites opart[0][q mapping]? Avoid: write zt to OFF_O1T-based
  // region instead (4MB is too small for [8][4096][256]); use OFF_KT..? kt/vct are dead
  // after attn. zt needs 16MB; kt+vct+qt+o1t = 16.7MB contiguous from OFF_KT. Use that.
  unsigned short* ztx  = (unsigned short*)(ws + OFF_KT);   // 16.7MB region, dead post-attn

  prep_weights_kernel<<<1904, 256, 0, stream>>>(wdw1, wdw2, wc1, bng, bnb, bnm, bnv,
                                                wc2, wk, wv, wq7, wq11, wc1b, wc2b,
                                                bc1, wkb, wvb);
  prep_x_kernel<<<dim3(128, 4), 256, 0, stream>>>(x, xt);
  kv_kernel<<<1024, 256, 0, stream>>>(xt, wkb, wvb, bk, bv, ktp, vct);
  conv_q_both_kernel<<<dim3(64, 8), 256, 0, stream>>>(xt, wq7, wq11, bdw1, bdw2, qtp);
  if (big){
    attn_kernel<4><<<dim3(32, 8, 4), 256, 0, stream>>>(qtp, ktp, vct, opart, mlp);
    c1m_kernel<4><<<dim3(64, 8), 256, 0, stream>>>(opart, mlp, xt, wc1b, bc1, ztx);
  } else {
    attn_kernel<2><<<dim3(32, 8, 2), 256, 0, stream>>>(qtp, ktp, vct, opart, mlp);
    c1m_kernel<2><<<dim3(64, 8), 256, 0, stream>>>(opart, mlp, xt, wc1b, bc1, ztx);
  }
  c2_kernel<<<dim3(32, 8), 256, 0, stream>>>(ztx, wc2b, bc2, (float*)d_out);
  (void)zt;
}